// Round 4
// baseline (1173.896 us; speedup 1.0000x reference)
//
#include <hip/hip_runtime.h>
#include <math.h>

// Problem constants
#define NN     302      // state dim (N_ROOMS + 2)
#define MM     301      // input dim (N_ROOMS + 1)
#define NROOMS 300
#define NP     320      // padded dim: 320 = 8 waves * 40 cols = 5 * 64 rows
#define TS     59999    // number of steps
#define KN     2001     // tout knots
#define DTH    30.0f

// Time-chunking
#define L_CHUNK 256     // steps per chunk (level 1)
#define N_CHUNK 235     // ceil(59999/256) chunks
#define N_BND   234     // boundary steps (G_0..G_233 produce Y_1..Y_234)
#define NB_PAD  240     // padded boundary count (15 groups of 16)
#define N_GRP   15      // level-2 groups

// Workspace layout (in floats)
#define WS_M    0        // 102400
#define WS_M2   102400   // 102400
#define WS_E    204800   // 102400
#define WS_P    307200   // 102400
#define WS_UV   409600   // 1600
#define WS_B0C  411200   // 640
#define WS_Q    411840   // 320
#define WS_TAU  412160   // 240000 (float4 x 59999)
#define WS_W    652160   // 5 x 256 x 320 = 409600
#define WS_G    1061760  // 240 x 320 = 76800 (padded)
#define WS_Y    1138560  // 235 x 320 = 75200
#define WS_Z    1213760  // 16 x 320 = 5120
#define WS_SA   1218880  // 120 x 320 = 38400
#define WS_SB   1257280  // 60 x 320 = 19200
#define WS_PL   1276480  // 102400  P^256 row-major fp32
#define WS_PL16 1378880  // 102400  P^4096 row-major fp32
#define WS_PD0  1481280  // 204800 (fp64 ping)
#define WS_PD1  1686080  // 204800 (fp64 pong)
#define WS_PT   1890880  // 13 x 102400 = 1331200 (transposed fp32 powers)
                         // total 3222080 floats = 12.9 MB

#define ENGINE_BOUNDS __launch_bounds__(512) __attribute__((amdgpu_waves_per_eu(2, 2)))

// ---------------------------------------------------------------------------
// Build W elementwise (coalesced): M = DTH * W, zero-padded to 320x320.
__global__ void sigw_kernel(const float* __restrict__ params,
                            const float* __restrict__ tlo,
                            const float* __restrict__ thi,
                            float* __restrict__ M)
{
    const int i = blockIdx.x * 256 + threadIdx.x;
    if (i >= NP * NP) return;
    const int r = i / NP, c = i - r * NP;
    float v = 0.0f;
    if (r < NN && c < NN) {
        const int idx = r * NN + c;
        const float x = 1.0f / (1.0f + expf(-params[idx]));
        v = DTH * (tlo[idx] + (thi[idx] - tlo[idx]) * x);
    }
    M[i] = v;
}

// Fix diagonal: M[r][r] -= sum_c |M[r][c]|  (wave-per-row reduction)
__global__ void rowfix_kernel(float* __restrict__ M)
{
    const int r = blockIdx.x;
    const int l = threadIdx.x;
    float s = 0.0f;
    #pragma unroll
    for (int k = 0; k < 5; ++k) s += fabsf(M[r * NP + l + 64 * k]);
    #pragma unroll
    for (int off = 32; off > 0; off >>= 1) s += __shfl_xor(s, off, 64);
    if (l == 0) M[r * NP + r] -= s;
}

__global__ void q_kernel(const float* __restrict__ params,
                         const float* __restrict__ tlo,
                         const float* __restrict__ thi,
                         float* __restrict__ Q)
{
    const int q = threadIdx.x;
    if (q < NROOMS) {
        const int idx = NN * NN + q;
        const float x = 1.0f / (1.0f + expf(-params[idx]));
        Q[q] = tlo[idx] + (thi[idx] - tlo[idx]) * x;
    }
}

// b0 = B[:,0], c = B[:,1:] @ Q  (wave per row)
__global__ void b0c_kernel(const float* __restrict__ B, const float* __restrict__ Q,
                           float* __restrict__ b0c)
{
    const int r = blockIdx.x;
    const int l = threadIdx.x;
    if (r >= NN) {
        if (l == 0) { b0c[r] = 0.0f; b0c[NP + r] = 0.0f; }
        return;
    }
    float s = 0.0f;
    for (int q = l; q < NROOMS; q += 64) s = fmaf(B[r * MM + 1 + q], Q[q], s);
    #pragma unroll
    for (int off = 32; off > 0; off >>= 1) s += __shfl_xor(s, off, 64);
    if (l == 0) { b0c[r] = B[r * MM]; b0c[NP + r] = s; }
}

// ---------------------------------------------------------------------------
// fp32 matmul 320^3, 4 rows per thread: grid (5, 80), block 64.
__global__ void matmul4r(const float* __restrict__ A, const float* __restrict__ B,
                         float* __restrict__ C)
{
    const int c = blockIdx.x * 64 + threadIdx.x;
    const int r0 = blockIdx.y * 4;
    const float* Ar = A + (size_t)r0 * NP;
    float a0 = 0.f, a1 = 0.f, a2 = 0.f, a3 = 0.f;
    #pragma unroll 4
    for (int k = 0; k < NP; ++k) {
        const float b = B[(size_t)k * NP + c];
        a0 = fmaf(Ar[k], b, a0);
        a1 = fmaf(Ar[NP + k], b, a1);
        a2 = fmaf(Ar[2 * NP + k], b, a2);
        a3 = fmaf(Ar[3 * NP + k], b, a3);
    }
    C[(size_t)r0 * NP + c] = a0;
    C[(size_t)(r0 + 1) * NP + c] = a1;
    C[(size_t)(r0 + 2) * NP + c] = a2;
    C[(size_t)(r0 + 3) * NP + c] = a3;
}

// E = M/6 + M2/24 (elementwise)
__global__ void combineE(const float* __restrict__ M, const float* __restrict__ M2,
                         float* __restrict__ E)
{
    const int i = blockIdx.x * 256 + threadIdx.x;
    if (i >= NP * NP) return;
    E[i] = (1.0f / 6.0f) * M[i] + (1.0f / 24.0f) * M2[i];
}

// P = M2 @ E + (I + M + M2/2)
__global__ void matmulP(const float* __restrict__ M2, const float* __restrict__ E,
                        const float* __restrict__ M, float* __restrict__ P)
{
    const int c = blockIdx.x * 64 + threadIdx.x;
    const int r0 = blockIdx.y * 4;
    const float* Ar = M2 + (size_t)r0 * NP;
    float a0 = 0.f, a1 = 0.f, a2 = 0.f, a3 = 0.f;
    #pragma unroll 4
    for (int k = 0; k < NP; ++k) {
        const float b = E[(size_t)k * NP + c];
        a0 = fmaf(Ar[k], b, a0);
        a1 = fmaf(Ar[NP + k], b, a1);
        a2 = fmaf(Ar[2 * NP + k], b, a2);
        a3 = fmaf(Ar[3 * NP + k], b, a3);
    }
    float acc[4] = {a0, a1, a2, a3};
    #pragma unroll
    for (int u = 0; u < 4; ++u) {
        const int r = r0 + u;
        const size_t idx = (size_t)r * NP + c;
        float v = acc[u] + M[idx] + 0.5f * M2[idx];
        if (r == c && r < NN) v += 1.0f;
        P[idx] = v;
    }
}

// ---------------------------------------------------------------------------
// forcing vectors; seeds W level-0 and writes out[0:302] = iv
__global__ void vec_kernel(const float* __restrict__ M, const float* __restrict__ b0c,
                           float* __restrict__ uv, const float* __restrict__ iv,
                           float* __restrict__ W, float* __restrict__ out)
{
    __shared__ float v[NP];
    const int tid = threadIdx.x;  // 320
    const float s = DTH / 8.0f;
    const float* Mr = M + tid * NP;

    const float b0 = b0c[tid];
    v[tid] = b0; __syncthreads();
    float mb = 0.0f;  for (int j = 0; j < NP; ++j) mb  = fmaf(Mr[j], v[j], mb);
    __syncthreads(); v[tid] = mb;  __syncthreads();
    float m2b = 0.0f; for (int j = 0; j < NP; ++j) m2b = fmaf(Mr[j], v[j], m2b);
    __syncthreads(); v[tid] = m2b; __syncthreads();
    float m3b = 0.0f; for (int j = 0; j < NP; ++j) m3b = fmaf(Mr[j], v[j], m3b);

    const float u1 = s * (b0 + mb + (1.0f / 3.0f) * (m2b + m3b));
    const float u2 = s * (3.0f * b0 + 2.0f * mb + m2b);
    const float u3 = s * (3.0f * b0 + mb);
    const float u4 = s * b0;

    const float cc = b0c[NP + tid];
    __syncthreads(); v[tid] = cc;  __syncthreads();
    float mc = 0.0f;  for (int j = 0; j < NP; ++j) mc  = fmaf(Mr[j], v[j], mc);
    __syncthreads(); v[tid] = mc;  __syncthreads();
    float m2c = 0.0f; for (int j = 0; j < NP; ++j) m2c = fmaf(Mr[j], v[j], m2c);
    __syncthreads(); v[tid] = m2c; __syncthreads();
    float m3c = 0.0f; for (int j = 0; j < NP; ++j) m3c = fmaf(Mr[j], v[j], m3c);

    const float dd = s * (8.0f * cc + 4.0f * mc + (4.0f / 3.0f) * m2c + (1.0f / 3.0f) * m3c);

    uv[tid]          = u1;
    uv[NP + tid]     = u2;
    uv[2 * NP + tid] = u3;
    uv[3 * NP + tid] = u4;
    uv[4 * NP + tid] = dd;

    W[(size_t)(0 << 8) * NP + tid] = dd;
    W[(size_t)(1 << 8) * NP + tid] = u1;
    W[(size_t)(2 << 8) * NP + tid] = u2;
    W[(size_t)(3 << 8) * NP + tid] = u3;
    W[(size_t)(4 << 8) * NP + tid] = u4;

    if (tid < NN) out[tid] = iv[tid];
}

// ---------------------------------------------------------------------------
// per-step Tout interp coefficients (np.interp clone)
__global__ void tau_kernel(const float* __restrict__ tout_t,
                           const float* __restrict__ tout_v,
                           const int* __restrict__ t0p,
                           float4* __restrict__ tau)
{
    const int n = blockIdx.x * 256 + threadIdx.x;
    if (n >= TS) return;
    const float tbase = 30.0f * (float)n + (float)(*t0p);
    float r[4];
    #pragma unroll
    for (int st = 0; st < 4; ++st) {
        const float x = tbase + 10.0f * (float)st;
        float res;
        if (x <= tout_t[0])            res = tout_v[0];
        else if (x >= tout_t[KN - 1])  res = tout_v[KN - 1];
        else {
            int k = (int)(x * (1.0f / 900.0f));
            if (k > KN - 2) k = KN - 2;
            if (k < 0) k = 0;
            if (x < tout_t[k] && k > 0) --k;
            else if (x >= tout_t[k + 1] && k < KN - 2) ++k;
            const float tk = tout_t[k], tk1 = tout_t[k + 1];
            const float wgt = (x - tk) / (tk1 - tk);
            res = tout_v[k] + wgt * (tout_v[k + 1] - tout_v[k]);
        }
        r[st] = res;
    }
    tau[n] = make_float4(r[0], r[1], r[2], r[3]);
}

// ---------------------------------------------------------------------------
// cast P fp32 -> PD fp64 and PT0 fp32 transpose
__global__ void castT_kernel(const float* __restrict__ P, double* __restrict__ PD,
                             float* __restrict__ PTf)
{
    const int i = blockIdx.x * 256 + threadIdx.x;
    if (i >= NP * NP) return;
    const int r = i / NP, c = i - r * NP;
    const float v = P[i];
    PD[i] = (double)v;
    PTf[(size_t)c * NP + r] = v;
}

// fp64 square + fp32 transposed copy of result
__global__ void sqT_kernel(const double* __restrict__ A, double* __restrict__ C,
                           float* __restrict__ CTf)
{
    const int c = blockIdx.x * 64 + threadIdx.x;
    const int r0 = blockIdx.y * 4;
    const double* Ar = A + (size_t)r0 * NP;
    double a0 = 0., a1 = 0., a2 = 0., a3 = 0.;
    #pragma unroll 4
    for (int k = 0; k < NP; ++k) {
        const double b = A[(size_t)k * NP + c];
        a0 = fma(Ar[k], b, a0);
        a1 = fma(Ar[NP + k], b, a1);
        a2 = fma(Ar[2 * NP + k], b, a2);
        a3 = fma(Ar[3 * NP + k], b, a3);
    }
    C[(size_t)r0 * NP + c] = a0;
    C[(size_t)(r0 + 1) * NP + c] = a1;
    C[(size_t)(r0 + 2) * NP + c] = a2;
    C[(size_t)(r0 + 3) * NP + c] = a3;
    float4 t = make_float4((float)a0, (float)a1, (float)a2, (float)a3);
    *(float4*)(CTf + (size_t)c * NP + r0) = t;
}

__global__ void cast_d2f(const double* __restrict__ s, float* __restrict__ d)
{
    const int i = blockIdx.x * 256 + threadIdx.x;
    if (i < NP * NP) d[i] = (float)s[i];
}

// ---------------------------------------------------------------------------
// Doubling level j: W[v][2^j + mo] = P^(2^j) @ W[v][mo].  PTf transposed.
__global__ __launch_bounds__(320) void double_kernel(const float* __restrict__ PTf,
                                                     float* __restrict__ W, int j)
{
    const int tid = threadIdx.x;       // 320
    const int nc = 5 << j;
    const int c0 = blockIdx.x * 4;
    __shared__ float ys[4][NP];
    #pragma unroll
    for (int u = 0; u < 4; ++u) {
        const int ci = c0 + u;
        float val = 0.0f;
        if (ci < nc) {
            const int v = ci >> j, mo = ci & ((1 << j) - 1);
            val = W[(size_t)((v << 8) + mo) * NP + tid];
        }
        ys[u][tid] = val;
    }
    __syncthreads();
    float a0 = 0.f, a1 = 0.f, a2 = 0.f, a3 = 0.f;
    #pragma unroll 4
    for (int k = 0; k < NP; ++k) {
        const float p = PTf[(size_t)k * NP + tid];
        a0 = fmaf(p, ys[0][k], a0);
        a1 = fmaf(p, ys[1][k], a1);
        a2 = fmaf(p, ys[2][k], a2);
        a3 = fmaf(p, ys[3][k], a3);
    }
    const float acc[4] = {a0, a1, a2, a3};
    #pragma unroll
    for (int u = 0; u < 4; ++u) {
        const int ci = c0 + u;
        if (ci < nc) {
            const int v = ci >> j, mo = ci & ((1 << j) - 1);
            W[(size_t)((v << 8) + (1 << j) + mo) * NP + tid] = acc[u];
        }
    }
}

// ---------------------------------------------------------------------------
// G_c = sum_m (Wd[m] + tau.x*W1[m] + ...), grid (5, 240) x 64; pad c>=234 -> 0.
__global__ void gsum_kernel(const float* __restrict__ W,
                            const float4* __restrict__ tau,
                            float* __restrict__ G)
{
    const int r = blockIdx.x * 64 + threadIdx.x;
    const int c = blockIdx.y;
    if (c >= N_BND) { G[(size_t)c * NP + r] = 0.0f; return; }
    const float* W0 = W;
    const float* W1 = W + 1 * (size_t)L_CHUNK * NP;
    const float* W2 = W + 2 * (size_t)L_CHUNK * NP;
    const float* W3 = W + 3 * (size_t)L_CHUNK * NP;
    const float* W4 = W + 4 * (size_t)L_CHUNK * NP;
    const int nbase = c * L_CHUNK + L_CHUNK - 1;
    float g = 0.f;
    for (int m = 0; m < L_CHUNK; ++m) {
        const float4 a = tau[nbase - m];
        const size_t o = (size_t)m * NP + r;
        float t = W0[o];
        t = fmaf(a.x, W1[o], t);
        t = fmaf(a.y, W2[o], t);
        t = fmaf(a.z, W3[o], t);
        t = fmaf(a.w, W4[o], t);
        g += t;
    }
    G[(size_t)c * NP + r] = g;
}

// ---------------------------------------------------------------------------
// Pair-combine for level-2 scan: Sout[k] = H^(2^i) @ Sin[2k] + Sin[2k+1].
__global__ __launch_bounds__(320) void pair_kernel(const float* __restrict__ PTf,
                                                   const float* __restrict__ Sin,
                                                   float* __restrict__ Sout, int npairs)
{
    const int tid = threadIdx.x;       // 320
    const int c0 = blockIdx.x * 4;
    __shared__ float ys[4][NP];
    #pragma unroll
    for (int u = 0; u < 4; ++u) {
        const int k = c0 + u;
        ys[u][tid] = (k < npairs) ? Sin[(size_t)(2 * k) * NP + tid] : 0.0f;
    }
    __syncthreads();
    float a0 = 0.f, a1 = 0.f, a2 = 0.f, a3 = 0.f;
    #pragma unroll 4
    for (int k = 0; k < NP; ++k) {
        const float p = PTf[(size_t)k * NP + tid];
        a0 = fmaf(p, ys[0][k], a0);
        a1 = fmaf(p, ys[1][k], a1);
        a2 = fmaf(p, ys[2][k], a2);
        a3 = fmaf(p, ys[3][k], a3);
    }
    const float acc[4] = {a0, a1, a2, a3};
    #pragma unroll
    for (int u = 0; u < 4; ++u) {
        const int k = c0 + u;
        if (k < npairs)
            Sout[(size_t)k * NP + tid] = acc[u] + Sin[(size_t)(2 * k + 1) * NP + tid];
    }
}

// ---------------------------------------------------------------------------
// Matvec engine (512 thr = 8 waves; wave w owns cols [40w,40w+40); lane l rows l+64k)
__device__ __forceinline__ void load_pfrag(const float* __restrict__ Psrc,
                                           float p[5][40], int l, int w)
{
    #pragma unroll
    for (int k = 0; k < 5; ++k) {
        const float* Pr = Psrc + (size_t)(l + 64 * k) * NP + 40 * w;
        #pragma unroll
        for (int j4 = 0; j4 < 10; ++j4) {
            const float4 v4 = *(const float4*)(Pr + 4 * j4);
            p[k][4 * j4 + 0] = v4.x; p[k][4 * j4 + 1] = v4.y;
            p[k][4 * j4 + 2] = v4.z; p[k][4 * j4 + 3] = v4.w;
        }
    }
}

__device__ __forceinline__ float step_matvec(const float p[5][40],
                                             const float* __restrict__ ybuf,
                                             float* __restrict__ partial,
                                             int tid, int w, int l)
{
    float acc0 = 0.f, acc1 = 0.f, acc2 = 0.f, acc3 = 0.f, acc4 = 0.f;
    const float* yb = ybuf + 40 * w;
    #pragma unroll
    for (int j4 = 0; j4 < 10; ++j4) {
        const float4 yv = *(const float4*)(yb + 4 * j4);
        const int j = 4 * j4;
        acc0 = fmaf(p[0][j + 0], yv.x, acc0); acc0 = fmaf(p[0][j + 1], yv.y, acc0);
        acc0 = fmaf(p[0][j + 2], yv.z, acc0); acc0 = fmaf(p[0][j + 3], yv.w, acc0);
        acc1 = fmaf(p[1][j + 0], yv.x, acc1); acc1 = fmaf(p[1][j + 1], yv.y, acc1);
        acc1 = fmaf(p[1][j + 2], yv.z, acc1); acc1 = fmaf(p[1][j + 3], yv.w, acc1);
        acc2 = fmaf(p[2][j + 0], yv.x, acc2); acc2 = fmaf(p[2][j + 1], yv.y, acc2);
        acc2 = fmaf(p[2][j + 2], yv.z, acc2); acc2 = fmaf(p[2][j + 3], yv.w, acc2);
        acc3 = fmaf(p[3][j + 0], yv.x, acc3); acc3 = fmaf(p[3][j + 1], yv.y, acc3);
        acc3 = fmaf(p[3][j + 2], yv.z, acc3); acc3 = fmaf(p[3][j + 3], yv.w, acc3);
        acc4 = fmaf(p[4][j + 0], yv.x, acc4); acc4 = fmaf(p[4][j + 1], yv.y, acc4);
        acc4 = fmaf(p[4][j + 2], yv.z, acc4); acc4 = fmaf(p[4][j + 3], yv.w, acc4);
    }
    float* pw = partial + w * NP;
    pw[l]       = acc0;
    pw[l + 64]  = acc1;
    pw[l + 128] = acc2;
    pw[l + 192] = acc3;
    pw[l + 256] = acc4;
    __syncthreads();
    float s = 0.f;
    if (tid < NP) {
        s = partial[0 * NP + tid] + partial[1 * NP + tid] + partial[2 * NP + tid]
          + partial[3 * NP + tid] + partial[4 * NP + tid] + partial[5 * NP + tid]
          + partial[6 * NP + tid] + partial[7 * NP + tid];
    }
    return s;
}

// ---------------------------------------------------------------------------
// Level-2 boundary: Z_{g+1} = P^4096 Z_g + S4_g.  1 WG x 512, 15 steps.
__global__ ENGINE_BOUNDS void bscan_kernel(
    const float* __restrict__ PL16, const float* __restrict__ S4,
    const float* __restrict__ iv, float* __restrict__ Z)
{
    const int tid = threadIdx.x;
    const int w = tid >> 6, l = tid & 63;
    float p[5][40];
    load_pfrag(PL16, p, l, w);

    __shared__ float ybuf[NP];
    __shared__ float partial[8 * NP];
    if (tid < NP) { const float y0 = (tid < NN) ? iv[tid] : 0.f; ybuf[tid] = y0; Z[tid] = y0; }
    __syncthreads();

    for (int g = 0; g < N_GRP; ++g) {
        const float s = step_matvec(p, ybuf, partial, tid, w, l);
        if (tid < NP) {
            const float yn = s + S4[(size_t)g * NP + tid];
            ybuf[tid] = yn;
            Z[(size_t)(g + 1) * NP + tid] = yn;
        }
        __syncthreads();
    }
}

// ---------------------------------------------------------------------------
// Level-2 refill: Y_{16g+i+1} = P^256 Y_{16g+i} + G_{16g+i}.  15 WGs x 512.
__global__ ENGINE_BOUNDS void brefill_kernel(
    const float* __restrict__ PL, const float* __restrict__ G,
    const float* __restrict__ Z, float* __restrict__ Y)
{
    const int tid = threadIdx.x;
    const int w = tid >> 6, l = tid & 63;
    float p[5][40];
    load_pfrag(PL, p, l, w);

    __shared__ float ybuf[NP];
    __shared__ float partial[8 * NP];
    const int g = blockIdx.x;
    if (tid < NP) {
        const float z = Z[(size_t)g * NP + tid];
        ybuf[tid] = z;
        if (g == 0) Y[tid] = z;
    }
    __syncthreads();

    for (int i = 0; i < 16; ++i) {
        const int idx = 16 * g + i;
        if (idx >= N_BND) break;            // block-uniform
        const float s = step_matvec(p, ybuf, partial, tid, w, l);
        if (tid < NP) {
            const float yn = s + G[(size_t)idx * NP + tid];
            ybuf[tid] = yn;
            Y[(size_t)(idx + 1) * NP + tid] = yn;
        }
        __syncthreads();
    }
}

// ---------------------------------------------------------------------------
// Level-1 refill: grid 235 WGs x 512; WG c runs steps [256c, min(256c+256,TS)).
__global__ ENGINE_BOUNDS void refill_kernel(
    const float* __restrict__ P, const float* __restrict__ uv,
    const float4* __restrict__ tau, const float* __restrict__ Y,
    float* __restrict__ out)
{
    const int tid = threadIdx.x;
    const int w = tid >> 6, l = tid & 63;
    float p[5][40];
    load_pfrag(P, p, l, w);

    float du0 = 0.f, du1 = 0.f, du2 = 0.f, du3 = 0.f, dd = 0.f;
    if (tid < NP) {
        du0 = uv[tid]; du1 = uv[NP + tid]; du2 = uv[2 * NP + tid];
        du3 = uv[3 * NP + tid]; dd = uv[4 * NP + tid];
    }

    __shared__ float ybuf[NP];
    __shared__ float partial[8 * NP];
    const int c = blockIdx.x;
    if (tid < NP) ybuf[tid] = Y[(size_t)c * NP + tid];
    __syncthreads();

    const int n0 = c * L_CHUNK;
    const int n1 = (n0 + L_CHUNK < TS) ? (n0 + L_CHUNK) : TS;
    for (int n = n0; n < n1; ++n) {
        const float s = step_matvec(p, ybuf, partial, tid, w, l);
        if (tid < NP) {
            const float4 a = tau[n];
            float yn = s + dd;
            yn = fmaf(a.x, du0, yn);
            yn = fmaf(a.y, du1, yn);
            yn = fmaf(a.z, du2, yn);
            yn = fmaf(a.w, du3, yn);
            ybuf[tid] = yn;
            if (tid < NN) out[(size_t)(n + 1) * NN + tid] = yn;
        }
        __syncthreads();
    }
}

// ---------------------------------------------------------------------------
extern "C" void kernel_launch(void* const* d_in, const int* in_sizes, int n_in,
                              void* d_out, int out_size, void* d_ws, size_t ws_size,
                              hipStream_t stream)
{
    const float* params = (const float*)d_in[0];
    const float* tlo    = (const float*)d_in[1];
    const float* thi    = (const float*)d_in[2];
    const float* B      = (const float*)d_in[3];
    const float* tout_t = (const float*)d_in[4];
    const float* tout_v = (const float*)d_in[5];
    const float* iv     = (const float*)d_in[6];
    const int*   t0     = (const int*)d_in[8];
    float* out = (float*)d_out;
    float* ws  = (float*)d_ws;

    float*  M    = ws + WS_M;
    float*  M2   = ws + WS_M2;
    float*  E    = ws + WS_E;
    float*  P    = ws + WS_P;
    float*  UV   = ws + WS_UV;
    float*  B0C  = ws + WS_B0C;
    float*  Q    = ws + WS_Q;
    float4* TAU  = (float4*)(ws + WS_TAU);
    float*  W    = ws + WS_W;
    float*  G    = ws + WS_G;
    float*  Y    = ws + WS_Y;
    float*  Z    = ws + WS_Z;
    float*  SA   = ws + WS_SA;
    float*  SB   = ws + WS_SB;
    float*  PL   = ws + WS_PL;
    float*  PL16 = ws + WS_PL16;
    double* PD[2] = { (double*)(ws + WS_PD0), (double*)(ws + WS_PD1) };
    float*  PT   = ws + WS_PT;     // PT + j*NP*NP = transpose of P^(2^j)

    const int NE = (NP * NP + 255) / 256;   // 400 blocks

    // Phase A: model build
    sigw_kernel<<<NE, 256, 0, stream>>>(params, tlo, thi, M);
    rowfix_kernel<<<NP, 64, 0, stream>>>(M);
    q_kernel<<<1, 320, 0, stream>>>(params, tlo, thi, Q);
    b0c_kernel<<<NP, 64, 0, stream>>>(B, Q, B0C);

    // Propagator P = I + M + M2/2 + M2@(M/6 + M2/24)
    matmul4r<<<dim3(5, 80), 64, 0, stream>>>(M, M, M2);
    combineE<<<NE, 256, 0, stream>>>(M, M2, E);
    matmulP<<<dim3(5, 80), 64, 0, stream>>>(M2, E, M, P);

    // Forcing vectors (+W seed, +out row 0) and tau table
    vec_kernel<<<1, NP, 0, stream>>>(M, B0C, UV, iv, W, out);
    tau_kernel<<<(TS + 255) / 256, 256, 0, stream>>>(tout_t, tout_v, t0, TAU);

    // Squaring ladder (fp64): PT[j] = (P^(2^j))^T fp32; W doubling rides j<8.
    castT_kernel<<<NE, 256, 0, stream>>>(P, PD[0], PT);
    for (int j = 0; j < 12; ++j) {
        if (j < 8) {
            const int nc = 5 << j;
            double_kernel<<<(nc + 3) / 4, NP, 0, stream>>>(PT + (size_t)j * NP * NP, W, j);
        }
        sqT_kernel<<<dim3(5, 80), 64, 0, stream>>>(PD[j & 1], PD[(j + 1) & 1],
                                                   PT + (size_t)(j + 1) * NP * NP);
        if (j == 7) cast_d2f<<<NE, 256, 0, stream>>>(PD[0], PL);     // P^256
    }
    cast_d2f<<<NE, 256, 0, stream>>>(PD[0], PL16);                   // P^4096

    // Per-chunk aggregated forcing (padded to 240)
    gsum_kernel<<<dim3(5, NB_PAD), 64, 0, stream>>>(W, TAU, G);

    // Level-2 scan of G into per-16-group sums S4 (SA after two ping-pongs)
    pair_kernel<<<30, NP, 0, stream>>>(PT + (size_t)8 * NP * NP,  G,  SA, 120);  // H^1
    pair_kernel<<<15, NP, 0, stream>>>(PT + (size_t)9 * NP * NP,  SA, SB, 60);   // H^2
    pair_kernel<<<8,  NP, 0, stream>>>(PT + (size_t)10 * NP * NP, SB, SA, 30);   // H^4
    pair_kernel<<<4,  NP, 0, stream>>>(PT + (size_t)11 * NP * NP, SA, SB, 15);   // H^8

    // Level-2 boundary chain (15 steps) + level-2 refill of Y (15 WGs x 16)
    bscan_kernel<<<1, 512, 0, stream>>>(PL16, SB, iv, Z);
    brefill_kernel<<<N_GRP, 512, 0, stream>>>(PL, G, Z, Y);

    // Level-1 parallel refill
    refill_kernel<<<N_CHUNK, 512, 0, stream>>>(P, UV, TAU, Y, out);
}

// Round 5
// 1134.313 us; speedup vs baseline: 1.0349x; 1.0349x over previous
//
#include <hip/hip_runtime.h>
#include <math.h>

// Problem constants
#define NN     302      // state dim (N_ROOMS + 2)
#define MM     301      // input dim (N_ROOMS + 1)
#define NROOMS 300
#define NP     320      // padded dim
#define TS     59999    // number of steps
#define KN     2001     // tout knots
#define DTH    30.0f

// Time-chunking
#define L_CHUNK 256     // steps per chunk (level 1)
#define N_CHUNK 235     // ceil(59999/256) chunks
#define N_BND   234     // boundary steps
#define NB_PAD  240     // padded boundary count (15 groups of 16)
#define N_GRP   15      // level-2 groups

// Workspace layout (in floats)
#define WS_M    0        // 102400
#define WS_M2   102400   // 102400
#define WS_E    204800   // 102400
#define WS_P    307200   // 102400
#define WS_UV   409600   // 1600
#define WS_B0C  411200   // 640
#define WS_Q    411840   // 320
#define WS_TAU  412160   // 240000 (float4 x 59999)
#define WS_W    652160   // 5 x 256 x 320 = 409600
#define WS_G    1061760  // 240 x 320 = 76800
#define WS_Y    1138560  // 235 x 320 = 75200
#define WS_Z    1213760  // 16 x 320 = 5120
#define WS_SA   1218880  // 120 x 320 = 38400
#define WS_SB   1257280  // 60 x 320 = 19200
#define WS_PL   1276480  // 102400  P^256 row-major
#define WS_PA   1378880  // 102400  ladder ping
#define WS_PB   1481280  // 102400  ladder pong (ends as P^4096)
#define WS_PT   1583680  // 13 x 102400 = 1331200 (transposed powers, slot j = (P^(2^j))^T)
                         // total 2914880 floats = 11.66 MB

// 1024-thread engine: 16 waves; wave w owns cols [20w,20w+20); lane l owns rows l+64k (k<5).
// P fragment = 100 VGPRs/thread -> fits the 128-VGPR cap of __launch_bounds__(1024),
// avoiding the AGPR spill (round 3/4: 116 VGPR + per-FMA v_accvgpr_read = 2x slowdown).
#define ENGINE_BOUNDS __launch_bounds__(1024)

// ---------------------------------------------------------------------------
// Build W elementwise (coalesced): M = DTH * W, zero-padded to 320x320.
__global__ void sigw_kernel(const float* __restrict__ params,
                            const float* __restrict__ tlo,
                            const float* __restrict__ thi,
                            float* __restrict__ M)
{
    const int i = blockIdx.x * 256 + threadIdx.x;
    if (i >= NP * NP) return;
    const int r = i / NP, c = i - r * NP;
    float v = 0.0f;
    if (r < NN && c < NN) {
        const int idx = r * NN + c;
        const float x = 1.0f / (1.0f + expf(-params[idx]));
        v = DTH * (tlo[idx] + (thi[idx] - tlo[idx]) * x);
    }
    M[i] = v;
}

// Fix diagonal: M[r][r] -= sum_c |M[r][c]|
__global__ void rowfix_kernel(float* __restrict__ M)
{
    const int r = blockIdx.x;
    const int l = threadIdx.x;
    float s = 0.0f;
    #pragma unroll
    for (int k = 0; k < 5; ++k) s += fabsf(M[r * NP + l + 64 * k]);
    #pragma unroll
    for (int off = 32; off > 0; off >>= 1) s += __shfl_xor(s, off, 64);
    if (l == 0) M[r * NP + r] -= s;
}

__global__ void q_kernel(const float* __restrict__ params,
                         const float* __restrict__ tlo,
                         const float* __restrict__ thi,
                         float* __restrict__ Q)
{
    const int q = threadIdx.x;
    if (q < NROOMS) {
        const int idx = NN * NN + q;
        const float x = 1.0f / (1.0f + expf(-params[idx]));
        Q[q] = tlo[idx] + (thi[idx] - tlo[idx]) * x;
    }
}

// b0 = B[:,0], c = B[:,1:] @ Q  (wave per row)
__global__ void b0c_kernel(const float* __restrict__ B, const float* __restrict__ Q,
                           float* __restrict__ b0c)
{
    const int r = blockIdx.x;
    const int l = threadIdx.x;
    if (r >= NN) {
        if (l == 0) { b0c[r] = 0.0f; b0c[NP + r] = 0.0f; }
        return;
    }
    float s = 0.0f;
    for (int q = l; q < NROOMS; q += 64) s = fmaf(B[r * MM + 1 + q], Q[q], s);
    #pragma unroll
    for (int off = 32; off > 0; off >>= 1) s += __shfl_xor(s, off, 64);
    if (l == 0) { b0c[r] = B[r * MM]; b0c[NP + r] = s; }
}

// ---------------------------------------------------------------------------
// fp32 matmul 320^3, 4 rows per thread: grid (5, 80), block 64.
__global__ void matmul4r(const float* __restrict__ A, const float* __restrict__ B,
                         float* __restrict__ C)
{
    const int c = blockIdx.x * 64 + threadIdx.x;
    const int r0 = blockIdx.y * 4;
    const float* Ar = A + (size_t)r0 * NP;
    float a0 = 0.f, a1 = 0.f, a2 = 0.f, a3 = 0.f;
    #pragma unroll 4
    for (int k = 0; k < NP; ++k) {
        const float b = B[(size_t)k * NP + c];
        a0 = fmaf(Ar[k], b, a0);
        a1 = fmaf(Ar[NP + k], b, a1);
        a2 = fmaf(Ar[2 * NP + k], b, a2);
        a3 = fmaf(Ar[3 * NP + k], b, a3);
    }
    C[(size_t)r0 * NP + c] = a0;
    C[(size_t)(r0 + 1) * NP + c] = a1;
    C[(size_t)(r0 + 2) * NP + c] = a2;
    C[(size_t)(r0 + 3) * NP + c] = a3;
}

// E = M/6 + M2/24 (elementwise)
__global__ void combineE(const float* __restrict__ M, const float* __restrict__ M2,
                         float* __restrict__ E)
{
    const int i = blockIdx.x * 256 + threadIdx.x;
    if (i >= NP * NP) return;
    E[i] = (1.0f / 6.0f) * M[i] + (1.0f / 24.0f) * M2[i];
}

// P = M2 @ E + (I + M + M2/2)
__global__ void matmulP(const float* __restrict__ M2, const float* __restrict__ E,
                        const float* __restrict__ M, float* __restrict__ P)
{
    const int c = blockIdx.x * 64 + threadIdx.x;
    const int r0 = blockIdx.y * 4;
    const float* Ar = M2 + (size_t)r0 * NP;
    float a0 = 0.f, a1 = 0.f, a2 = 0.f, a3 = 0.f;
    #pragma unroll 4
    for (int k = 0; k < NP; ++k) {
        const float b = E[(size_t)k * NP + c];
        a0 = fmaf(Ar[k], b, a0);
        a1 = fmaf(Ar[NP + k], b, a1);
        a2 = fmaf(Ar[2 * NP + k], b, a2);
        a3 = fmaf(Ar[3 * NP + k], b, a3);
    }
    float acc[4] = {a0, a1, a2, a3};
    #pragma unroll
    for (int u = 0; u < 4; ++u) {
        const int r = r0 + u;
        const size_t idx = (size_t)r * NP + c;
        float v = acc[u] + M[idx] + 0.5f * M2[idx];
        if (r == c && r < NN) v += 1.0f;
        P[idx] = v;
    }
}

// ---------------------------------------------------------------------------
// forcing vectors; seeds W level-0 and writes out[0:302] = iv
__global__ void vec_kernel(const float* __restrict__ M, const float* __restrict__ b0c,
                           float* __restrict__ uv, const float* __restrict__ iv,
                           float* __restrict__ W, float* __restrict__ out)
{
    __shared__ float v[NP];
    const int tid = threadIdx.x;  // 320
    const float s = DTH / 8.0f;
    const float* Mr = M + tid * NP;

    const float b0 = b0c[tid];
    v[tid] = b0; __syncthreads();
    float mb = 0.0f;  for (int j = 0; j < NP; ++j) mb  = fmaf(Mr[j], v[j], mb);
    __syncthreads(); v[tid] = mb;  __syncthreads();
    float m2b = 0.0f; for (int j = 0; j < NP; ++j) m2b = fmaf(Mr[j], v[j], m2b);
    __syncthreads(); v[tid] = m2b; __syncthreads();
    float m3b = 0.0f; for (int j = 0; j < NP; ++j) m3b = fmaf(Mr[j], v[j], m3b);

    const float u1 = s * (b0 + mb + (1.0f / 3.0f) * (m2b + m3b));
    const float u2 = s * (3.0f * b0 + 2.0f * mb + m2b);
    const float u3 = s * (3.0f * b0 + mb);
    const float u4 = s * b0;

    const float cc = b0c[NP + tid];
    __syncthreads(); v[tid] = cc;  __syncthreads();
    float mc = 0.0f;  for (int j = 0; j < NP; ++j) mc  = fmaf(Mr[j], v[j], mc);
    __syncthreads(); v[tid] = mc;  __syncthreads();
    float m2c = 0.0f; for (int j = 0; j < NP; ++j) m2c = fmaf(Mr[j], v[j], m2c);
    __syncthreads(); v[tid] = m2c; __syncthreads();
    float m3c = 0.0f; for (int j = 0; j < NP; ++j) m3c = fmaf(Mr[j], v[j], m3c);

    const float dd = s * (8.0f * cc + 4.0f * mc + (4.0f / 3.0f) * m2c + (1.0f / 3.0f) * m3c);

    uv[tid]          = u1;
    uv[NP + tid]     = u2;
    uv[2 * NP + tid] = u3;
    uv[3 * NP + tid] = u4;
    uv[4 * NP + tid] = dd;

    W[(size_t)(0 << 8) * NP + tid] = dd;
    W[(size_t)(1 << 8) * NP + tid] = u1;
    W[(size_t)(2 << 8) * NP + tid] = u2;
    W[(size_t)(3 << 8) * NP + tid] = u3;
    W[(size_t)(4 << 8) * NP + tid] = u4;

    if (tid < NN) out[tid] = iv[tid];
}

// ---------------------------------------------------------------------------
// per-step Tout interp coefficients (np.interp clone)
__global__ void tau_kernel(const float* __restrict__ tout_t,
                           const float* __restrict__ tout_v,
                           const int* __restrict__ t0p,
                           float4* __restrict__ tau)
{
    const int n = blockIdx.x * 256 + threadIdx.x;
    if (n >= TS) return;
    const float tbase = 30.0f * (float)n + (float)(*t0p);
    float r[4];
    #pragma unroll
    for (int st = 0; st < 4; ++st) {
        const float x = tbase + 10.0f * (float)st;
        float res;
        if (x <= tout_t[0])            res = tout_v[0];
        else if (x >= tout_t[KN - 1])  res = tout_v[KN - 1];
        else {
            int k = (int)(x * (1.0f / 900.0f));
            if (k > KN - 2) k = KN - 2;
            if (k < 0) k = 0;
            if (x < tout_t[k] && k > 0) --k;
            else if (x >= tout_t[k + 1] && k < KN - 2) ++k;
            const float tk = tout_t[k], tk1 = tout_t[k + 1];
            const float wgt = (x - tk) / (tk1 - tk);
            res = tout_v[k] + wgt * (tout_v[k + 1] - tout_v[k]);
        }
        r[st] = res;
    }
    tau[n] = make_float4(r[0], r[1], r[2], r[3]);
}

// ---------------------------------------------------------------------------
// transpose: PT = P^T
__global__ void transpose_kernel(const float* __restrict__ P, float* __restrict__ PT)
{
    const int i = blockIdx.x * 256 + threadIdx.x;
    if (i >= NP * NP) return;
    const int r = i / NP, c = i - r * NP;
    PT[(size_t)c * NP + r] = P[i];
}

// elementwise copy (save P^256 out of the ping-pong)
__global__ void copy_kernel(const float* __restrict__ s, float* __restrict__ d)
{
    const int i = blockIdx.x * 256 + threadIdx.x;
    if (i < NP * NP) d[i] = s[i];
}

// fp32 square with fused transposed output: C = A@A, CT = C^T.
// grid (5, 80), block 256: warp u -> row r0+u, lane -> col. A-row loads are
// wave-uniform (scalar path); A-col loads coalesced.
__global__ void sq32_kernel(const float* __restrict__ A, float* __restrict__ C,
                            float* __restrict__ CT)
{
    const int c = blockIdx.x * 64 + (threadIdx.x & 63);
    const int r = blockIdx.y * 4 + (threadIdx.x >> 6);
    const float* Ar = A + (size_t)r * NP;
    float acc = 0.f;
    #pragma unroll 4
    for (int k = 0; k < NP; ++k)
        acc = fmaf(Ar[k], A[(size_t)k * NP + c], acc);
    C[(size_t)r * NP + c] = acc;
    CT[(size_t)c * NP + r] = acc;
}

// ---------------------------------------------------------------------------
// Doubling level j: W[v][2^j + mo] = P^(2^j) @ W[v][mo].  PTf transposed.
__global__ __launch_bounds__(320) void double_kernel(const float* __restrict__ PTf,
                                                     float* __restrict__ W, int j)
{
    const int tid = threadIdx.x;       // 320
    const int nc = 5 << j;
    const int c0 = blockIdx.x * 4;
    __shared__ float ys[4][NP];
    #pragma unroll
    for (int u = 0; u < 4; ++u) {
        const int ci = c0 + u;
        float val = 0.0f;
        if (ci < nc) {
            const int v = ci >> j, mo = ci & ((1 << j) - 1);
            val = W[(size_t)((v << 8) + mo) * NP + tid];
        }
        ys[u][tid] = val;
    }
    __syncthreads();
    float a0 = 0.f, a1 = 0.f, a2 = 0.f, a3 = 0.f;
    #pragma unroll 4
    for (int k = 0; k < NP; ++k) {
        const float p = PTf[(size_t)k * NP + tid];
        a0 = fmaf(p, ys[0][k], a0);
        a1 = fmaf(p, ys[1][k], a1);
        a2 = fmaf(p, ys[2][k], a2);
        a3 = fmaf(p, ys[3][k], a3);
    }
    const float acc[4] = {a0, a1, a2, a3};
    #pragma unroll
    for (int u = 0; u < 4; ++u) {
        const int ci = c0 + u;
        if (ci < nc) {
            const int v = ci >> j, mo = ci & ((1 << j) - 1);
            W[(size_t)((v << 8) + (1 << j) + mo) * NP + tid] = acc[u];
        }
    }
}

// ---------------------------------------------------------------------------
// G_c = sum_m (Wd[m] + tau.x*W1[m] + ...), grid (5, 240) x 64; pad c>=234 -> 0.
__global__ void gsum_kernel(const float* __restrict__ W,
                            const float4* __restrict__ tau,
                            float* __restrict__ G)
{
    const int r = blockIdx.x * 64 + threadIdx.x;
    const int c = blockIdx.y;
    if (c >= N_BND) { G[(size_t)c * NP + r] = 0.0f; return; }
    const float* W0 = W;
    const float* W1 = W + 1 * (size_t)L_CHUNK * NP;
    const float* W2 = W + 2 * (size_t)L_CHUNK * NP;
    const float* W3 = W + 3 * (size_t)L_CHUNK * NP;
    const float* W4 = W + 4 * (size_t)L_CHUNK * NP;
    const int nbase = c * L_CHUNK + L_CHUNK - 1;
    float g = 0.f;
    for (int m = 0; m < L_CHUNK; ++m) {
        const float4 a = tau[nbase - m];
        const size_t o = (size_t)m * NP + r;
        float t = W0[o];
        t = fmaf(a.x, W1[o], t);
        t = fmaf(a.y, W2[o], t);
        t = fmaf(a.z, W3[o], t);
        t = fmaf(a.w, W4[o], t);
        g += t;
    }
    G[(size_t)c * NP + r] = g;
}

// ---------------------------------------------------------------------------
// Pair-combine for level-2 scan: Sout[k] = H^(2^i) @ Sin[2k] + Sin[2k+1].
__global__ __launch_bounds__(320) void pair_kernel(const float* __restrict__ PTf,
                                                   const float* __restrict__ Sin,
                                                   float* __restrict__ Sout, int npairs)
{
    const int tid = threadIdx.x;       // 320
    const int c0 = blockIdx.x * 4;
    __shared__ float ys[4][NP];
    #pragma unroll
    for (int u = 0; u < 4; ++u) {
        const int k = c0 + u;
        ys[u][tid] = (k < npairs) ? Sin[(size_t)(2 * k) * NP + tid] : 0.0f;
    }
    __syncthreads();
    float a0 = 0.f, a1 = 0.f, a2 = 0.f, a3 = 0.f;
    #pragma unroll 4
    for (int k = 0; k < NP; ++k) {
        const float p = PTf[(size_t)k * NP + tid];
        a0 = fmaf(p, ys[0][k], a0);
        a1 = fmaf(p, ys[1][k], a1);
        a2 = fmaf(p, ys[2][k], a2);
        a3 = fmaf(p, ys[3][k], a3);
    }
    const float acc[4] = {a0, a1, a2, a3};
    #pragma unroll
    for (int u = 0; u < 4; ++u) {
        const int k = c0 + u;
        if (k < npairs)
            Sout[(size_t)k * NP + tid] = acc[u] + Sin[(size_t)(2 * k + 1) * NP + tid];
    }
}

// ---------------------------------------------------------------------------
// 1024-thread matvec engine. Wave w (0..15) owns cols [20w,20w+20);
// lane l owns rows {l+64k}, k<5. P fragment = 100 VGPRs/thread.
__device__ __forceinline__ void load_pfrag(const float* __restrict__ Psrc,
                                           float p[5][20], int l, int w)
{
    #pragma unroll
    for (int k = 0; k < 5; ++k) {
        const float* Pr = Psrc + (size_t)(l + 64 * k) * NP + 20 * w;
        #pragma unroll
        for (int j4 = 0; j4 < 5; ++j4) {
            const float4 v4 = *(const float4*)(Pr + 4 * j4);
            p[k][4 * j4 + 0] = v4.x; p[k][4 * j4 + 1] = v4.y;
            p[k][4 * j4 + 2] = v4.z; p[k][4 * j4 + 3] = v4.w;
        }
    }
}

// One matvec: returns (P*y)[tid] for tid<NP. One internal __syncthreads();
// caller must __syncthreads() after updating ybuf.
__device__ __forceinline__ float step_matvec(const float p[5][20],
                                             const float* __restrict__ ybuf,
                                             float* __restrict__ partial,
                                             int tid, int w, int l)
{
    float acc0 = 0.f, acc1 = 0.f, acc2 = 0.f, acc3 = 0.f, acc4 = 0.f;
    const float* yb = ybuf + 20 * w;
    #pragma unroll
    for (int j4 = 0; j4 < 5; ++j4) {
        const float4 yv = *(const float4*)(yb + 4 * j4);
        const int j = 4 * j4;
        acc0 = fmaf(p[0][j + 0], yv.x, acc0); acc0 = fmaf(p[0][j + 1], yv.y, acc0);
        acc0 = fmaf(p[0][j + 2], yv.z, acc0); acc0 = fmaf(p[0][j + 3], yv.w, acc0);
        acc1 = fmaf(p[1][j + 0], yv.x, acc1); acc1 = fmaf(p[1][j + 1], yv.y, acc1);
        acc1 = fmaf(p[1][j + 2], yv.z, acc1); acc1 = fmaf(p[1][j + 3], yv.w, acc1);
        acc2 = fmaf(p[2][j + 0], yv.x, acc2); acc2 = fmaf(p[2][j + 1], yv.y, acc2);
        acc2 = fmaf(p[2][j + 2], yv.z, acc2); acc2 = fmaf(p[2][j + 3], yv.w, acc2);
        acc3 = fmaf(p[3][j + 0], yv.x, acc3); acc3 = fmaf(p[3][j + 1], yv.y, acc3);
        acc3 = fmaf(p[3][j + 2], yv.z, acc3); acc3 = fmaf(p[3][j + 3], yv.w, acc3);
        acc4 = fmaf(p[4][j + 0], yv.x, acc4); acc4 = fmaf(p[4][j + 1], yv.y, acc4);
        acc4 = fmaf(p[4][j + 2], yv.z, acc4); acc4 = fmaf(p[4][j + 3], yv.w, acc4);
    }
    float* pw = partial + w * NP;
    pw[l]       = acc0;
    pw[l + 64]  = acc1;
    pw[l + 128] = acc2;
    pw[l + 192] = acc3;
    pw[l + 256] = acc4;
    __syncthreads();
    float s = 0.f;
    if (tid < NP) {
        #pragma unroll
        for (int k = 0; k < 16; ++k) s += partial[k * NP + tid];
    }
    return s;
}

// ---------------------------------------------------------------------------
// Level-2 boundary: Z_{g+1} = P^4096 Z_g + S4_g.  1 WG x 1024, 15 steps.
__global__ ENGINE_BOUNDS void bscan_kernel(
    const float* __restrict__ PL16, const float* __restrict__ S4,
    const float* __restrict__ iv, float* __restrict__ Z)
{
    const int tid = threadIdx.x;
    const int w = tid >> 6, l = tid & 63;
    float p[5][20];
    load_pfrag(PL16, p, l, w);

    __shared__ float ybuf[NP];
    __shared__ float partial[16 * NP];
    if (tid < NP) { const float y0 = (tid < NN) ? iv[tid] : 0.f; ybuf[tid] = y0; Z[tid] = y0; }
    __syncthreads();

    for (int g = 0; g < N_GRP; ++g) {
        const float s = step_matvec(p, ybuf, partial, tid, w, l);
        if (tid < NP) {
            const float yn = s + S4[(size_t)g * NP + tid];
            ybuf[tid] = yn;
            Z[(size_t)(g + 1) * NP + tid] = yn;
        }
        __syncthreads();
    }
}

// ---------------------------------------------------------------------------
// Level-2 refill: Y_{16g+i+1} = P^256 Y_{16g+i} + G_{16g+i}.  15 WGs x 1024.
__global__ ENGINE_BOUNDS void brefill_kernel(
    const float* __restrict__ PL, const float* __restrict__ G,
    const float* __restrict__ Z, float* __restrict__ Y)
{
    const int tid = threadIdx.x;
    const int w = tid >> 6, l = tid & 63;
    float p[5][20];
    load_pfrag(PL, p, l, w);

    __shared__ float ybuf[NP];
    __shared__ float partial[16 * NP];
    const int g = blockIdx.x;
    if (tid < NP) {
        const float z = Z[(size_t)g * NP + tid];
        ybuf[tid] = z;
        if (g == 0) Y[tid] = z;
    }
    __syncthreads();

    for (int i = 0; i < 16; ++i) {
        const int idx = 16 * g + i;
        if (idx >= N_BND) break;            // block-uniform
        const float s = step_matvec(p, ybuf, partial, tid, w, l);
        if (tid < NP) {
            const float yn = s + G[(size_t)idx * NP + tid];
            ybuf[tid] = yn;
            Y[(size_t)(idx + 1) * NP + tid] = yn;
        }
        __syncthreads();
    }
}

// ---------------------------------------------------------------------------
// Level-1 refill: grid 235 WGs x 1024; WG c runs steps [256c, min(256c+256,TS)).
__global__ ENGINE_BOUNDS void refill_kernel(
    const float* __restrict__ P, const float* __restrict__ uv,
    const float4* __restrict__ tau, const float* __restrict__ Y,
    float* __restrict__ out)
{
    const int tid = threadIdx.x;
    const int w = tid >> 6, l = tid & 63;
    float p[5][20];
    load_pfrag(P, p, l, w);

    float du0 = 0.f, du1 = 0.f, du2 = 0.f, du3 = 0.f, dd = 0.f;
    if (tid < NP) {
        du0 = uv[tid]; du1 = uv[NP + tid]; du2 = uv[2 * NP + tid];
        du3 = uv[3 * NP + tid]; dd = uv[4 * NP + tid];
    }

    __shared__ float ybuf[NP];
    __shared__ float partial[16 * NP];
    const int c = blockIdx.x;
    if (tid < NP) ybuf[tid] = Y[(size_t)c * NP + tid];
    __syncthreads();

    const int n0 = c * L_CHUNK;
    const int n1 = (n0 + L_CHUNK < TS) ? (n0 + L_CHUNK) : TS;
    for (int n = n0; n < n1; ++n) {
        const float s = step_matvec(p, ybuf, partial, tid, w, l);
        if (tid < NP) {
            const float4 a = tau[n];
            float yn = s + dd;
            yn = fmaf(a.x, du0, yn);
            yn = fmaf(a.y, du1, yn);
            yn = fmaf(a.z, du2, yn);
            yn = fmaf(a.w, du3, yn);
            ybuf[tid] = yn;
            if (tid < NN) out[(size_t)(n + 1) * NN + tid] = yn;
        }
        __syncthreads();
    }
}

// ---------------------------------------------------------------------------
extern "C" void kernel_launch(void* const* d_in, const int* in_sizes, int n_in,
                              void* d_out, int out_size, void* d_ws, size_t ws_size,
                              hipStream_t stream)
{
    const float* params = (const float*)d_in[0];
    const float* tlo    = (const float*)d_in[1];
    const float* thi    = (const float*)d_in[2];
    const float* B      = (const float*)d_in[3];
    const float* tout_t = (const float*)d_in[4];
    const float* tout_v = (const float*)d_in[5];
    const float* iv     = (const float*)d_in[6];
    const int*   t0     = (const int*)d_in[8];
    float* out = (float*)d_out;
    float* ws  = (float*)d_ws;

    float*  M    = ws + WS_M;
    float*  M2   = ws + WS_M2;
    float*  E    = ws + WS_E;
    float*  P    = ws + WS_P;
    float*  UV   = ws + WS_UV;
    float*  B0C  = ws + WS_B0C;
    float*  Q    = ws + WS_Q;
    float4* TAU  = (float4*)(ws + WS_TAU);
    float*  W    = ws + WS_W;
    float*  G    = ws + WS_G;
    float*  Y    = ws + WS_Y;
    float*  Z    = ws + WS_Z;
    float*  SA   = ws + WS_SA;
    float*  SB   = ws + WS_SB;
    float*  PL   = ws + WS_PL;
    float*  PA   = ws + WS_PA;
    float*  PB   = ws + WS_PB;
    float*  PT   = ws + WS_PT;     // slot j: transpose of P^(2^j)

    const int NE = (NP * NP + 255) / 256;   // 400 blocks

    // Phase A: model build
    sigw_kernel<<<NE, 256, 0, stream>>>(params, tlo, thi, M);
    rowfix_kernel<<<NP, 64, 0, stream>>>(M);
    q_kernel<<<1, 320, 0, stream>>>(params, tlo, thi, Q);
    b0c_kernel<<<NP, 64, 0, stream>>>(B, Q, B0C);

    // Propagator P = I + M + M2/2 + M2@(M/6 + M2/24)
    matmul4r<<<dim3(5, 80), 64, 0, stream>>>(M, M, M2);
    combineE<<<NE, 256, 0, stream>>>(M, M2, E);
    matmulP<<<dim3(5, 80), 64, 0, stream>>>(M2, E, M, P);

    // Forcing vectors (+W seed, +out row 0) and tau table
    vec_kernel<<<1, NP, 0, stream>>>(M, B0C, UV, iv, W, out);
    tau_kernel<<<(TS + 255) / 256, 256, 0, stream>>>(tout_t, tout_v, t0, TAU);

    // fp32 squaring ladder; W doubling rides levels 0..7.
    // iter j: src=P^(2^j) -> dst=P^(2^(j+1)), PT[j+1]=dst^T. dst_j = (j odd ? PB : PA).
    transpose_kernel<<<NE, 256, 0, stream>>>(P, PT);
    const float* src = P;
    for (int j = 0; j < 12; ++j) {
        if (j < 8) {
            const int nc = 5 << j;
            double_kernel<<<(nc + 3) / 4, NP, 0, stream>>>(PT + (size_t)j * NP * NP, W, j);
        }
        float* dst = (j & 1) ? PB : PA;
        sq32_kernel<<<dim3(5, 80), 256, 0, stream>>>(src, dst, PT + (size_t)(j + 1) * NP * NP);
        if (j == 7) copy_kernel<<<NE, 256, 0, stream>>>(dst, PL);   // P^256
        src = dst;
    }
    // src == PB == P^4096 (untouched afterwards)

    // Per-chunk aggregated forcing (padded to 240)
    gsum_kernel<<<dim3(5, NB_PAD), 64, 0, stream>>>(W, TAU, G);

    // Level-2 scan of G into per-16-group sums (SB after 4 levels)
    pair_kernel<<<30, NP, 0, stream>>>(PT + (size_t)8 * NP * NP,  G,  SA, 120);  // H^1
    pair_kernel<<<15, NP, 0, stream>>>(PT + (size_t)9 * NP * NP,  SA, SB, 60);   // H^2
    pair_kernel<<<8,  NP, 0, stream>>>(PT + (size_t)10 * NP * NP, SB, SA, 30);   // H^4
    pair_kernel<<<4,  NP, 0, stream>>>(PT + (size_t)11 * NP * NP, SA, SB, 15);   // H^8

    // Level-2 boundary chain + level-2 refill of Y
    bscan_kernel<<<1, 1024, 0, stream>>>(PB, SB, iv, Z);
    brefill_kernel<<<N_GRP, 1024, 0, stream>>>(PL, G, Z, Y);

    // Level-1 parallel refill
    refill_kernel<<<N_CHUNK, 1024, 0, stream>>>(P, UV, TAU, Y, out);
}

// Round 6
// 1086.589 us; speedup vs baseline: 1.0803x; 1.0439x over previous
//
#include <hip/hip_runtime.h>
#include <math.h>

// Problem constants
#define NN     302      // state dim (N_ROOMS + 2)
#define MM     301      // input dim (N_ROOMS + 1)
#define NROOMS 300
#define NP     320      // padded dim
#define TS     59999    // number of steps
#define KN     2001     // tout knots
#define DTH    30.0f

// Time-chunking
#define L_CHUNK 256     // steps per chunk (level 1)
#define N_CHUNK 235     // ceil(59999/256) chunks
#define N_BND   234     // boundary steps
#define NB_PAD  240     // padded boundary count (15 groups of 16)
#define N_GRP   15      // level-2 groups

// Workspace layout (in floats)
#define WS_M    0        // 102400
#define WS_M2   102400   // 102400
#define WS_E    204800   // 102400
#define WS_P    307200   // 102400
#define WS_UV   409600   // 1600
#define WS_B0C  411200   // 640
#define WS_Q    411840   // 320
#define WS_TAU  412160   // 240000 (float4 x 59999)
#define WS_W    652160   // 5 x 256 x 320 = 409600
#define WS_G    1061760  // 240 x 320 = 76800
#define WS_Y    1138560  // 235 x 320 = 75200
#define WS_Z    1213760  // 16 x 320 = 5120
#define WS_SA   1218880  // 120 x 320 = 38400
#define WS_SB   1257280  // 60 x 320 = 19200
#define WS_PL   1276480  // 102400  P^256 row-major
#define WS_PA   1378880  // 102400  ladder ping
#define WS_PB   1481280  // 102400  ladder pong (ends as P^4096)
#define WS_PT   1583680  // 13 x 102400 = 1331200 (transposed powers)
#define WS_MT   2914880  // 102400  M^T
                         // total 3017280 floats = 12.07 MB

// 1024-thread engine: 16 waves; wave w owns cols [20w,20w+20); lane l owns rows
// l+64k (k<5). P fragment = 100 floats/thread. waves_per_eu(4,4) pins exactly
// 1 block/CU (128-VGPR cap); inline-asm v_fmac with "v" constraints forces the
// fragment into arch VGPRs (r5: compiler chose 64 VGPR + AGPR round-trip =
// one extra VALU op per FMA).
#define ENGINE_BOUNDS __launch_bounds__(1024) __attribute__((amdgpu_waves_per_eu(4, 4)))
#define FMAC(acc, a, b) asm("v_fmac_f32 %0, %1, %2" : "+v"(acc) : "v"(a), "v"(b))

// ---------------------------------------------------------------------------
// Build W elementwise (coalesced): M = DTH * W (and M^T), zero-padded.
__global__ void sigw_kernel(const float* __restrict__ params,
                            const float* __restrict__ tlo,
                            const float* __restrict__ thi,
                            float* __restrict__ M,
                            float* __restrict__ MT)
{
    const int i = blockIdx.x * 256 + threadIdx.x;
    if (i >= NP * NP) return;
    const int r = i / NP, c = i - r * NP;
    float v = 0.0f;
    if (r < NN && c < NN) {
        const int idx = r * NN + c;
        const float x = 1.0f / (1.0f + expf(-params[idx]));
        v = DTH * (tlo[idx] + (thi[idx] - tlo[idx]) * x);
    }
    M[i] = v;
    MT[(size_t)c * NP + r] = v;
}

// Fix diagonal: M[r][r] -= sum_c |M[r][c]| (and MT)
__global__ void rowfix_kernel(float* __restrict__ M, float* __restrict__ MT)
{
    const int r = blockIdx.x;
    const int l = threadIdx.x;
    float s = 0.0f;
    #pragma unroll
    for (int k = 0; k < 5; ++k) s += fabsf(M[r * NP + l + 64 * k]);
    #pragma unroll
    for (int off = 32; off > 0; off >>= 1) s += __shfl_xor(s, off, 64);
    if (l == 0) {
        const float nv = M[r * NP + r] - s;
        M[r * NP + r] = nv;
        MT[r * NP + r] = nv;
    }
}

__global__ void q_kernel(const float* __restrict__ params,
                         const float* __restrict__ tlo,
                         const float* __restrict__ thi,
                         float* __restrict__ Q)
{
    const int q = threadIdx.x;
    if (q < NROOMS) {
        const int idx = NN * NN + q;
        const float x = 1.0f / (1.0f + expf(-params[idx]));
        Q[q] = tlo[idx] + (thi[idx] - tlo[idx]) * x;
    }
}

// b0 = B[:,0], c = B[:,1:] @ Q  (wave per row)
__global__ void b0c_kernel(const float* __restrict__ B, const float* __restrict__ Q,
                           float* __restrict__ b0c)
{
    const int r = blockIdx.x;
    const int l = threadIdx.x;
    if (r >= NN) {
        if (l == 0) { b0c[r] = 0.0f; b0c[NP + r] = 0.0f; }
        return;
    }
    float s = 0.0f;
    for (int q = l; q < NROOMS; q += 64) s = fmaf(B[r * MM + 1 + q], Q[q], s);
    #pragma unroll
    for (int off = 32; off > 0; off >>= 1) s += __shfl_xor(s, off, 64);
    if (l == 0) { b0c[r] = B[r * MM]; b0c[NP + r] = s; }
}

// ---------------------------------------------------------------------------
// fp32 matmul 320^3, 4 rows per thread: grid (5, 80), block 64.
__global__ void matmul4r(const float* __restrict__ A, const float* __restrict__ B,
                         float* __restrict__ C)
{
    const int c = blockIdx.x * 64 + threadIdx.x;
    const int r0 = blockIdx.y * 4;
    const float* Ar = A + (size_t)r0 * NP;
    float a0 = 0.f, a1 = 0.f, a2 = 0.f, a3 = 0.f;
    #pragma unroll 4
    for (int k = 0; k < NP; ++k) {
        const float b = B[(size_t)k * NP + c];
        a0 = fmaf(Ar[k], b, a0);
        a1 = fmaf(Ar[NP + k], b, a1);
        a2 = fmaf(Ar[2 * NP + k], b, a2);
        a3 = fmaf(Ar[3 * NP + k], b, a3);
    }
    C[(size_t)r0 * NP + c] = a0;
    C[(size_t)(r0 + 1) * NP + c] = a1;
    C[(size_t)(r0 + 2) * NP + c] = a2;
    C[(size_t)(r0 + 3) * NP + c] = a3;
}

// E = M/6 + M2/24 (elementwise)
__global__ void combineE(const float* __restrict__ M, const float* __restrict__ M2,
                         float* __restrict__ E)
{
    const int i = blockIdx.x * 256 + threadIdx.x;
    if (i >= NP * NP) return;
    E[i] = (1.0f / 6.0f) * M[i] + (1.0f / 24.0f) * M2[i];
}

// P = M2 @ E + (I + M + M2/2)
__global__ void matmulP(const float* __restrict__ M2, const float* __restrict__ E,
                        const float* __restrict__ M, float* __restrict__ P)
{
    const int c = blockIdx.x * 64 + threadIdx.x;
    const int r0 = blockIdx.y * 4;
    const float* Ar = M2 + (size_t)r0 * NP;
    float a0 = 0.f, a1 = 0.f, a2 = 0.f, a3 = 0.f;
    #pragma unroll 4
    for (int k = 0; k < NP; ++k) {
        const float b = E[(size_t)k * NP + c];
        a0 = fmaf(Ar[k], b, a0);
        a1 = fmaf(Ar[NP + k], b, a1);
        a2 = fmaf(Ar[2 * NP + k], b, a2);
        a3 = fmaf(Ar[3 * NP + k], b, a3);
    }
    float acc[4] = {a0, a1, a2, a3};
    #pragma unroll
    for (int u = 0; u < 4; ++u) {
        const int r = r0 + u;
        const size_t idx = (size_t)r * NP + c;
        float v = acc[u] + M[idx] + 0.5f * M2[idx];
        if (r == c && r < NN) v += 1.0f;
        P[idx] = v;
    }
}

// ---------------------------------------------------------------------------
// forcing vectors via 3 coalesced column-matvec passes (b & c chains
// interleaved); seeds W level-0 and writes out[0:302] = iv.
__global__ __launch_bounds__(320) void vec_kernel(
    const float* __restrict__ MT, const float* __restrict__ b0c,
    float* __restrict__ uv, const float* __restrict__ iv,
    float* __restrict__ W, float* __restrict__ out)
{
    __shared__ float ysB[NP], ysC[NP];
    const int tid = threadIdx.x;  // 320
    const float s = DTH / 8.0f;

    const float b0 = b0c[tid];
    const float cc = b0c[NP + tid];
    ysB[tid] = b0; ysC[tid] = cc;
    __syncthreads();

    float mb, mc, m2b, m2c, m3b, m3c;
    {
        float aB = 0.f, aC = 0.f;
        for (int k = 0; k < NP; ++k) {
            const float a = MT[(size_t)k * NP + tid];   // coalesced
            aB = fmaf(a, ysB[k], aB);
            aC = fmaf(a, ysC[k], aC);
        }
        mb = aB; mc = aC;
    }
    __syncthreads(); ysB[tid] = mb; ysC[tid] = mc; __syncthreads();
    {
        float aB = 0.f, aC = 0.f;
        for (int k = 0; k < NP; ++k) {
            const float a = MT[(size_t)k * NP + tid];
            aB = fmaf(a, ysB[k], aB);
            aC = fmaf(a, ysC[k], aC);
        }
        m2b = aB; m2c = aC;
    }
    __syncthreads(); ysB[tid] = m2b; ysC[tid] = m2c; __syncthreads();
    {
        float aB = 0.f, aC = 0.f;
        for (int k = 0; k < NP; ++k) {
            const float a = MT[(size_t)k * NP + tid];
            aB = fmaf(a, ysB[k], aB);
            aC = fmaf(a, ysC[k], aC);
        }
        m3b = aB; m3c = aC;
    }

    const float u1 = s * (b0 + mb + (1.0f / 3.0f) * (m2b + m3b));
    const float u2 = s * (3.0f * b0 + 2.0f * mb + m2b);
    const float u3 = s * (3.0f * b0 + mb);
    const float u4 = s * b0;
    const float dd = s * (8.0f * cc + 4.0f * mc + (4.0f / 3.0f) * m2c + (1.0f / 3.0f) * m3c);

    uv[tid]          = u1;
    uv[NP + tid]     = u2;
    uv[2 * NP + tid] = u3;
    uv[3 * NP + tid] = u4;
    uv[4 * NP + tid] = dd;

    W[(size_t)(0 << 8) * NP + tid] = dd;
    W[(size_t)(1 << 8) * NP + tid] = u1;
    W[(size_t)(2 << 8) * NP + tid] = u2;
    W[(size_t)(3 << 8) * NP + tid] = u3;
    W[(size_t)(4 << 8) * NP + tid] = u4;

    if (tid < NN) out[tid] = iv[tid];
}

// ---------------------------------------------------------------------------
// per-step Tout interp coefficients (np.interp clone)
__global__ void tau_kernel(const float* __restrict__ tout_t,
                           const float* __restrict__ tout_v,
                           const int* __restrict__ t0p,
                           float4* __restrict__ tau)
{
    const int n = blockIdx.x * 256 + threadIdx.x;
    if (n >= TS) return;
    const float tbase = 30.0f * (float)n + (float)(*t0p);
    float r[4];
    #pragma unroll
    for (int st = 0; st < 4; ++st) {
        const float x = tbase + 10.0f * (float)st;
        float res;
        if (x <= tout_t[0])            res = tout_v[0];
        else if (x >= tout_t[KN - 1])  res = tout_v[KN - 1];
        else {
            int k = (int)(x * (1.0f / 900.0f));
            if (k > KN - 2) k = KN - 2;
            if (k < 0) k = 0;
            if (x < tout_t[k] && k > 0) --k;
            else if (x >= tout_t[k + 1] && k < KN - 2) ++k;
            const float tk = tout_t[k], tk1 = tout_t[k + 1];
            const float wgt = (x - tk) / (tk1 - tk);
            res = tout_v[k] + wgt * (tout_v[k + 1] - tout_v[k]);
        }
        r[st] = res;
    }
    tau[n] = make_float4(r[0], r[1], r[2], r[3]);
}

// ---------------------------------------------------------------------------
// transpose: PT = P^T
__global__ void transpose_kernel(const float* __restrict__ P, float* __restrict__ PT)
{
    const int i = blockIdx.x * 256 + threadIdx.x;
    if (i >= NP * NP) return;
    const int r = i / NP, c = i - r * NP;
    PT[(size_t)c * NP + r] = P[i];
}

// elementwise copy (save P^256 out of the ping-pong)
__global__ void copy_kernel(const float* __restrict__ s, float* __restrict__ d)
{
    const int i = blockIdx.x * 256 + threadIdx.x;
    if (i < NP * NP) d[i] = s[i];
}

// fp32 square with fused transposed output: C = A@A, CT = C^T.
__global__ void sq32_kernel(const float* __restrict__ A, float* __restrict__ C,
                            float* __restrict__ CT)
{
    const int c = blockIdx.x * 64 + (threadIdx.x & 63);
    const int r = blockIdx.y * 4 + (threadIdx.x >> 6);
    const float* Ar = A + (size_t)r * NP;
    float acc = 0.f;
    #pragma unroll 4
    for (int k = 0; k < NP; ++k)
        acc = fmaf(Ar[k], A[(size_t)k * NP + c], acc);
    C[(size_t)r * NP + c] = acc;
    CT[(size_t)c * NP + r] = acc;
}

// ---------------------------------------------------------------------------
// Doubling level j: W[v][2^j + mo] = P^(2^j) @ W[v][mo].  PTf transposed.
__global__ __launch_bounds__(320) void double_kernel(const float* __restrict__ PTf,
                                                     float* __restrict__ W, int j)
{
    const int tid = threadIdx.x;       // 320
    const int nc = 5 << j;
    const int c0 = blockIdx.x * 4;
    __shared__ float ys[4][NP];
    #pragma unroll
    for (int u = 0; u < 4; ++u) {
        const int ci = c0 + u;
        float val = 0.0f;
        if (ci < nc) {
            const int v = ci >> j, mo = ci & ((1 << j) - 1);
            val = W[(size_t)((v << 8) + mo) * NP + tid];
        }
        ys[u][tid] = val;
    }
    __syncthreads();
    float a0 = 0.f, a1 = 0.f, a2 = 0.f, a3 = 0.f;
    #pragma unroll 4
    for (int k = 0; k < NP; ++k) {
        const float p = PTf[(size_t)k * NP + tid];
        a0 = fmaf(p, ys[0][k], a0);
        a1 = fmaf(p, ys[1][k], a1);
        a2 = fmaf(p, ys[2][k], a2);
        a3 = fmaf(p, ys[3][k], a3);
    }
    const float acc[4] = {a0, a1, a2, a3};
    #pragma unroll
    for (int u = 0; u < 4; ++u) {
        const int ci = c0 + u;
        if (ci < nc) {
            const int v = ci >> j, mo = ci & ((1 << j) - 1);
            W[(size_t)((v << 8) + (1 << j) + mo) * NP + tid] = acc[u];
        }
    }
}

// ---------------------------------------------------------------------------
// G_c = sum_m (Wd[m] + tau.x*W1[m] + ...), grid (5, 240) x 64; pad c>=234 -> 0.
__global__ void gsum_kernel(const float* __restrict__ W,
                            const float4* __restrict__ tau,
                            float* __restrict__ G)
{
    const int r = blockIdx.x * 64 + threadIdx.x;
    const int c = blockIdx.y;
    if (c >= N_BND) { G[(size_t)c * NP + r] = 0.0f; return; }
    const float* W0 = W;
    const float* W1 = W + 1 * (size_t)L_CHUNK * NP;
    const float* W2 = W + 2 * (size_t)L_CHUNK * NP;
    const float* W3 = W + 3 * (size_t)L_CHUNK * NP;
    const float* W4 = W + 4 * (size_t)L_CHUNK * NP;
    const int nbase = c * L_CHUNK + L_CHUNK - 1;
    float g = 0.f;
    for (int m = 0; m < L_CHUNK; ++m) {
        const float4 a = tau[nbase - m];
        const size_t o = (size_t)m * NP + r;
        float t = W0[o];
        t = fmaf(a.x, W1[o], t);
        t = fmaf(a.y, W2[o], t);
        t = fmaf(a.z, W3[o], t);
        t = fmaf(a.w, W4[o], t);
        g += t;
    }
    G[(size_t)c * NP + r] = g;
}

// ---------------------------------------------------------------------------
// Pair-combine for level-2 scan: Sout[k] = H^(2^i) @ Sin[2k] + Sin[2k+1].
__global__ __launch_bounds__(320) void pair_kernel(const float* __restrict__ PTf,
                                                   const float* __restrict__ Sin,
                                                   float* __restrict__ Sout, int npairs)
{
    const int tid = threadIdx.x;       // 320
    const int c0 = blockIdx.x * 4;
    __shared__ float ys[4][NP];
    #pragma unroll
    for (int u = 0; u < 4; ++u) {
        const int k = c0 + u;
        ys[u][tid] = (k < npairs) ? Sin[(size_t)(2 * k) * NP + tid] : 0.0f;
    }
    __syncthreads();
    float a0 = 0.f, a1 = 0.f, a2 = 0.f, a3 = 0.f;
    #pragma unroll 4
    for (int k = 0; k < NP; ++k) {
        const float p = PTf[(size_t)k * NP + tid];
        a0 = fmaf(p, ys[0][k], a0);
        a1 = fmaf(p, ys[1][k], a1);
        a2 = fmaf(p, ys[2][k], a2);
        a3 = fmaf(p, ys[3][k], a3);
    }
    const float acc[4] = {a0, a1, a2, a3};
    #pragma unroll
    for (int u = 0; u < 4; ++u) {
        const int k = c0 + u;
        if (k < npairs)
            Sout[(size_t)k * NP + tid] = acc[u] + Sin[(size_t)(2 * k + 1) * NP + tid];
    }
}

// ---------------------------------------------------------------------------
// 1024-thread matvec engine. Wave w (0..15) owns cols [20w,20w+20);
// lane l owns rows {l+64k}, k<5. P fragment = 100 VGPRs/thread (asm-pinned).
__device__ __forceinline__ void load_pfrag(const float* __restrict__ Psrc,
                                           float p[5][20], int l, int w)
{
    #pragma unroll
    for (int k = 0; k < 5; ++k) {
        const float* Pr = Psrc + (size_t)(l + 64 * k) * NP + 20 * w;
        #pragma unroll
        for (int j4 = 0; j4 < 5; ++j4) {
            const float4 v4 = *(const float4*)(Pr + 4 * j4);
            p[k][4 * j4 + 0] = v4.x; p[k][4 * j4 + 1] = v4.y;
            p[k][4 * j4 + 2] = v4.z; p[k][4 * j4 + 3] = v4.w;
        }
    }
}

// One matvec: returns (P*y)[tid] for tid<NP. One internal __syncthreads();
// caller must __syncthreads() after updating ybuf.
__device__ __forceinline__ float step_matvec(float p[5][20],
                                             const float* __restrict__ ybuf,
                                             float* __restrict__ partial,
                                             int tid, int w, int l)
{
    float acc0 = 0.f, acc1 = 0.f, acc2 = 0.f, acc3 = 0.f, acc4 = 0.f;
    const float* yb = ybuf + 20 * w;
    #pragma unroll
    for (int j4 = 0; j4 < 5; ++j4) {
        const float4 yv = *(const float4*)(yb + 4 * j4);
        const int j = 4 * j4;
        FMAC(acc0, p[0][j + 0], yv.x); FMAC(acc0, p[0][j + 1], yv.y);
        FMAC(acc0, p[0][j + 2], yv.z); FMAC(acc0, p[0][j + 3], yv.w);
        FMAC(acc1, p[1][j + 0], yv.x); FMAC(acc1, p[1][j + 1], yv.y);
        FMAC(acc1, p[1][j + 2], yv.z); FMAC(acc1, p[1][j + 3], yv.w);
        FMAC(acc2, p[2][j + 0], yv.x); FMAC(acc2, p[2][j + 1], yv.y);
        FMAC(acc2, p[2][j + 2], yv.z); FMAC(acc2, p[2][j + 3], yv.w);
        FMAC(acc3, p[3][j + 0], yv.x); FMAC(acc3, p[3][j + 1], yv.y);
        FMAC(acc3, p[3][j + 2], yv.z); FMAC(acc3, p[3][j + 3], yv.w);
        FMAC(acc4, p[4][j + 0], yv.x); FMAC(acc4, p[4][j + 1], yv.y);
        FMAC(acc4, p[4][j + 2], yv.z); FMAC(acc4, p[4][j + 3], yv.w);
    }
    float* pw = partial + w * NP;
    pw[l]       = acc0;
    pw[l + 64]  = acc1;
    pw[l + 128] = acc2;
    pw[l + 192] = acc3;
    pw[l + 256] = acc4;
    __syncthreads();
    float s = 0.f;
    if (tid < NP) {
        #pragma unroll
        for (int k = 0; k < 16; ++k) s += partial[k * NP + tid];
    }
    return s;
}

// ---------------------------------------------------------------------------
// Level-2 boundary: Z_{g+1} = P^4096 Z_g + S4_g.  1 WG x 1024, 15 steps.
__global__ ENGINE_BOUNDS void bscan_kernel(
    const float* __restrict__ PL16, const float* __restrict__ S4,
    const float* __restrict__ iv, float* __restrict__ Z)
{
    const int tid = threadIdx.x;
    const int w = tid >> 6, l = tid & 63;
    float p[5][20];
    load_pfrag(PL16, p, l, w);

    __shared__ float ybuf[NP];
    __shared__ float partial[16 * NP];
    if (tid < NP) { const float y0 = (tid < NN) ? iv[tid] : 0.f; ybuf[tid] = y0; Z[tid] = y0; }
    __syncthreads();

    for (int g = 0; g < N_GRP; ++g) {
        const float s = step_matvec(p, ybuf, partial, tid, w, l);
        if (tid < NP) {
            const float yn = s + S4[(size_t)g * NP + tid];
            ybuf[tid] = yn;
            Z[(size_t)(g + 1) * NP + tid] = yn;
        }
        __syncthreads();
    }
}

// ---------------------------------------------------------------------------
// Level-2 refill: Y_{16g+i+1} = P^256 Y_{16g+i} + G_{16g+i}.  15 WGs x 1024.
__global__ ENGINE_BOUNDS void brefill_kernel(
    const float* __restrict__ PL, const float* __restrict__ G,
    const float* __restrict__ Z, float* __restrict__ Y)
{
    const int tid = threadIdx.x;
    const int w = tid >> 6, l = tid & 63;
    float p[5][20];
    load_pfrag(PL, p, l, w);

    __shared__ float ybuf[NP];
    __shared__ float partial[16 * NP];
    const int g = blockIdx.x;
    if (tid < NP) {
        const float z = Z[(size_t)g * NP + tid];
        ybuf[tid] = z;
        if (g == 0) Y[tid] = z;
    }
    __syncthreads();

    for (int i = 0; i < 16; ++i) {
        const int idx = 16 * g + i;
        if (idx >= N_BND) break;            // block-uniform
        const float s = step_matvec(p, ybuf, partial, tid, w, l);
        if (tid < NP) {
            const float yn = s + G[(size_t)idx * NP + tid];
            ybuf[tid] = yn;
            Y[(size_t)(idx + 1) * NP + tid] = yn;
        }
        __syncthreads();
    }
}

// ---------------------------------------------------------------------------
// Level-1 refill: grid 235 WGs x 1024; WG c runs steps [256c, min(256c+256,TS)).
__global__ ENGINE_BOUNDS void refill_kernel(
    const float* __restrict__ P, const float* __restrict__ uv,
    const float4* __restrict__ tau, const float* __restrict__ Y,
    float* __restrict__ out)
{
    const int tid = threadIdx.x;
    const int w = tid >> 6, l = tid & 63;
    float p[5][20];
    load_pfrag(P, p, l, w);

    float du0 = 0.f, du1 = 0.f, du2 = 0.f, du3 = 0.f, dd = 0.f;
    if (tid < NP) {
        du0 = uv[tid]; du1 = uv[NP + tid]; du2 = uv[2 * NP + tid];
        du3 = uv[3 * NP + tid]; dd = uv[4 * NP + tid];
    }

    __shared__ float ybuf[NP];
    __shared__ float partial[16 * NP];
    const int c = blockIdx.x;
    if (tid < NP) ybuf[tid] = Y[(size_t)c * NP + tid];
    __syncthreads();

    const int n0 = c * L_CHUNK;
    const int n1 = (n0 + L_CHUNK < TS) ? (n0 + L_CHUNK) : TS;
    for (int n = n0; n < n1; ++n) {
        const float s = step_matvec(p, ybuf, partial, tid, w, l);
        if (tid < NP) {
            const float4 a = tau[n];
            float yn = s + dd;
            yn = fmaf(a.x, du0, yn);
            yn = fmaf(a.y, du1, yn);
            yn = fmaf(a.z, du2, yn);
            yn = fmaf(a.w, du3, yn);
            ybuf[tid] = yn;
            if (tid < NN) out[(size_t)(n + 1) * NN + tid] = yn;
        }
        __syncthreads();
    }
}

// ---------------------------------------------------------------------------
extern "C" void kernel_launch(void* const* d_in, const int* in_sizes, int n_in,
                              void* d_out, int out_size, void* d_ws, size_t ws_size,
                              hipStream_t stream)
{
    const float* params = (const float*)d_in[0];
    const float* tlo    = (const float*)d_in[1];
    const float* thi    = (const float*)d_in[2];
    const float* B      = (const float*)d_in[3];
    const float* tout_t = (const float*)d_in[4];
    const float* tout_v = (const float*)d_in[5];
    const float* iv     = (const float*)d_in[6];
    const int*   t0     = (const int*)d_in[8];
    float* out = (float*)d_out;
    float* ws  = (float*)d_ws;

    float*  M    = ws + WS_M;
    float*  MT   = ws + WS_MT;
    float*  M2   = ws + WS_M2;
    float*  E    = ws + WS_E;
    float*  P    = ws + WS_P;
    float*  UV   = ws + WS_UV;
    float*  B0C  = ws + WS_B0C;
    float*  Q    = ws + WS_Q;
    float4* TAU  = (float4*)(ws + WS_TAU);
    float*  W    = ws + WS_W;
    float*  G    = ws + WS_G;
    float*  Y    = ws + WS_Y;
    float*  Z    = ws + WS_Z;
    float*  SA   = ws + WS_SA;
    float*  SB   = ws + WS_SB;
    float*  PL   = ws + WS_PL;
    float*  PA   = ws + WS_PA;
    float*  PB   = ws + WS_PB;
    float*  PT   = ws + WS_PT;     // slot j: transpose of P^(2^j)

    const int NE = (NP * NP + 255) / 256;   // 400 blocks

    // Phase A: model build
    sigw_kernel<<<NE, 256, 0, stream>>>(params, tlo, thi, M, MT);
    rowfix_kernel<<<NP, 64, 0, stream>>>(M, MT);
    q_kernel<<<1, 320, 0, stream>>>(params, tlo, thi, Q);
    b0c_kernel<<<NP, 64, 0, stream>>>(B, Q, B0C);

    // Propagator P = I + M + M2/2 + M2@(M/6 + M2/24)
    matmul4r<<<dim3(5, 80), 64, 0, stream>>>(M, M, M2);
    combineE<<<NE, 256, 0, stream>>>(M, M2, E);
    matmulP<<<dim3(5, 80), 64, 0, stream>>>(M2, E, M, P);

    // Forcing vectors (coalesced via MT) and tau table
    vec_kernel<<<1, NP, 0, stream>>>(MT, B0C, UV, iv, W, out);
    tau_kernel<<<(TS + 255) / 256, 256, 0, stream>>>(tout_t, tout_v, t0, TAU);

    // fp32 squaring ladder; W doubling rides levels 0..7.
    transpose_kernel<<<NE, 256, 0, stream>>>(P, PT);
    const float* src = P;
    for (int j = 0; j < 12; ++j) {
        if (j < 8) {
            const int nc = 5 << j;
            double_kernel<<<(nc + 3) / 4, NP, 0, stream>>>(PT + (size_t)j * NP * NP, W, j);
        }
        float* dst = (j & 1) ? PB : PA;
        sq32_kernel<<<dim3(5, 80), 256, 0, stream>>>(src, dst, PT + (size_t)(j + 1) * NP * NP);
        if (j == 7) copy_kernel<<<NE, 256, 0, stream>>>(dst, PL);   // P^256
        src = dst;
    }
    // src == PB == P^4096

    // Per-chunk aggregated forcing (padded to 240)
    gsum_kernel<<<dim3(5, NB_PAD), 64, 0, stream>>>(W, TAU, G);

    // Level-2 scan of G into per-16-group sums (SB after 4 levels)
    pair_kernel<<<30, NP, 0, stream>>>(PT + (size_t)8 * NP * NP,  G,  SA, 120);  // H^1
    pair_kernel<<<15, NP, 0, stream>>>(PT + (size_t)9 * NP * NP,  SA, SB, 60);   // H^2
    pair_kernel<<<8,  NP, 0, stream>>>(PT + (size_t)10 * NP * NP, SB, SA, 30);   // H^4
    pair_kernel<<<4,  NP, 0, stream>>>(PT + (size_t)11 * NP * NP, SA, SB, 15);   // H^8

    // Level-2 boundary chain + level-2 refill of Y
    bscan_kernel<<<1, 1024, 0, stream>>>(PB, SB, iv, Z);
    brefill_kernel<<<N_GRP, 1024, 0, stream>>>(PL, G, Z, Y);

    // Level-1 parallel refill
    refill_kernel<<<N_CHUNK, 1024, 0, stream>>>(P, UV, TAU, Y, out);
}

// Round 7
// 827.596 us; speedup vs baseline: 1.4184x; 1.3129x over previous
//
#include <hip/hip_runtime.h>
#include <math.h>

// Problem constants
#define NN     302      // state dim (N_ROOMS + 2)
#define MM     301      // input dim (N_ROOMS + 1)
#define NROOMS 300
#define NP     320      // padded dim
#define TS     59999    // number of steps
#define KN     2001     // tout knots
#define DTH    30.0f

// Time-chunking
#define L_CHUNK 256     // steps per chunk (level 1)
#define N_CHUNK 235     // ceil(59999/256) chunks
#define N_BND   234     // boundary steps
#define NB_PAD  240     // padded boundary count (15 groups of 16)
#define N_GRP   15      // level-2 groups

// Workspace layout (in floats)
#define WS_M    0        // 102400
#define WS_M2   102400   // 102400
#define WS_P    307200   // 102400
#define WS_UV   409600   // 1600
#define WS_B0C  411200   // 640
#define WS_TAU  412160   // 240000 (float4 x 59999)
#define WS_W    652160   // 5 x 256 x 320 = 409600
#define WS_G    1061760  // 240 x 320 = 76800
#define WS_Y    1138560  // 235 x 320 = 75200
#define WS_Z    1213760  // 16 x 320 = 5120
#define WS_SA   1218880  // 120 x 320 = 38400
#define WS_SB   1257280  // 60 x 320 = 19200
#define WS_PL   1276480  // 102400  P^256 row-major
#define WS_PA   1378880  // 102400  ladder ping
#define WS_PB   1481280  // 102400  ladder pong (ends as P^4096)
#define WS_PT   1583680  // 13 x 102400 (transposed powers, slot j = (P^(2^j))^T)
#define WS_MT   2914880  // 102400  M^T
                         // total 3017280 floats = 12.07 MB

typedef float vf2 __attribute__((ext_vector_type(2)));

// 512-thread engine: 8 waves; wave w owns cols [40w,40w+40); lane l owns rows
// l+64k (k<5). Fragment = 100 vf2 (200 regs). waves_per_eu(2,2) -> 256-reg
// budget. PIN asm breaks value provenance so the compiler cannot sink the
// fragment loads into the step loop (r5/r6: P was streamed from L2 every
// step, ~2900 cyc/step of L2 traffic — the real bottleneck, not AGPR moves).
#define ENGINE_BOUNDS __launch_bounds__(512) __attribute__((amdgpu_waves_per_eu(2, 2)))
#define PKFMA(acc, a, b) asm("v_pk_fma_f32 %0, %1, %2, %0" : "+v"(acc) : "v"(a), "v"(b))
#define PIN4(a, b, c, d) asm volatile("" : "+v"(a), "+v"(b), "+v"(c), "+v"(d))

// ---------------------------------------------------------------------------
// Fused build: one block per row r. M = DTH*W with diag -= DTH*sum|W[r,:]|;
// writes M and MT. 320 blocks x 320 threads.
__global__ __launch_bounds__(320) void buildrow_kernel(
    const float* __restrict__ params, const float* __restrict__ tlo,
    const float* __restrict__ thi, float* __restrict__ M, float* __restrict__ MT)
{
    const int r = blockIdx.x;
    const int c = threadIdx.x;
    float wv = 0.0f;
    if (r < NN && c < NN) {
        const int idx = r * NN + c;
        const float x = 1.0f / (1.0f + expf(-params[idx]));
        wv = tlo[idx] + (thi[idx] - tlo[idx]) * x;
    }
    __shared__ float red[5];
    float s = fabsf(wv);
    #pragma unroll
    for (int off = 32; off > 0; off >>= 1) s += __shfl_xor(s, off, 64);
    if ((c & 63) == 0) red[c >> 6] = s;
    __syncthreads();
    const float rs = red[0] + red[1] + red[2] + red[3] + red[4];
    float v = DTH * wv;
    if (r == c) v -= DTH * rs;
    M[r * NP + c] = v;
    MT[(size_t)c * NP + r] = v;
}

// b0 = B[:,0], c = B[:,1:] @ Q  (wave per row; Q recomputed per block)
__global__ void b0c_kernel(const float* __restrict__ params,
                           const float* __restrict__ tlo,
                           const float* __restrict__ thi,
                           const float* __restrict__ B, float* __restrict__ b0c)
{
    __shared__ float Qs[NROOMS];
    const int r = blockIdx.x;
    const int l = threadIdx.x;
    for (int q = l; q < NROOMS; q += 64) {
        const int idx = NN * NN + q;
        const float x = 1.0f / (1.0f + expf(-params[idx]));
        Qs[q] = tlo[idx] + (thi[idx] - tlo[idx]) * x;
    }
    __syncthreads();
    if (r >= NN) {
        if (l == 0) { b0c[r] = 0.0f; b0c[NP + r] = 0.0f; }
        return;
    }
    float s = 0.0f;
    for (int q = l; q < NROOMS; q += 64) s = fmaf(B[r * MM + 1 + q], Qs[q], s);
    #pragma unroll
    for (int off = 32; off > 0; off >>= 1) s += __shfl_xor(s, off, 64);
    if (l == 0) { b0c[r] = B[r * MM]; b0c[NP + r] = s; }
}

// ---------------------------------------------------------------------------
// fp32 matmul 320^3, 4 rows per thread: grid (5, 80), block 64.  (M2 = M@M)
__global__ void matmul4r(const float* __restrict__ A, const float* __restrict__ B,
                         float* __restrict__ C)
{
    const int c = blockIdx.x * 64 + threadIdx.x;
    const int r0 = blockIdx.y * 4;
    const float* Ar = A + (size_t)r0 * NP;
    float a0 = 0.f, a1 = 0.f, a2 = 0.f, a3 = 0.f;
    #pragma unroll 4
    for (int k = 0; k < NP; ++k) {
        const float b = B[(size_t)k * NP + c];
        a0 = fmaf(Ar[k], b, a0);
        a1 = fmaf(Ar[NP + k], b, a1);
        a2 = fmaf(Ar[2 * NP + k], b, a2);
        a3 = fmaf(Ar[3 * NP + k], b, a3);
    }
    C[(size_t)r0 * NP + c] = a0;
    C[(size_t)(r0 + 1) * NP + c] = a1;
    C[(size_t)(r0 + 2) * NP + c] = a2;
    C[(size_t)(r0 + 3) * NP + c] = a3;
}

// P = M2 @ (M/6 + M2/24) + (I + M + M2/2), E computed on the fly; also writes
// PT0 = P^T (ladder slot 0).
__global__ void matmulP(const float* __restrict__ M2, const float* __restrict__ M,
                        float* __restrict__ P, float* __restrict__ PT0)
{
    const int c = blockIdx.x * 64 + threadIdx.x;
    const int r0 = blockIdx.y * 4;
    const float* Ar = M2 + (size_t)r0 * NP;
    float a0 = 0.f, a1 = 0.f, a2 = 0.f, a3 = 0.f;
    #pragma unroll 4
    for (int k = 0; k < NP; ++k) {
        const size_t o = (size_t)k * NP + c;
        const float b = (1.0f / 6.0f) * M[o] + (1.0f / 24.0f) * M2[o];
        a0 = fmaf(Ar[k], b, a0);
        a1 = fmaf(Ar[NP + k], b, a1);
        a2 = fmaf(Ar[2 * NP + k], b, a2);
        a3 = fmaf(Ar[3 * NP + k], b, a3);
    }
    float acc[4] = {a0, a1, a2, a3};
    float4 t;
    #pragma unroll
    for (int u = 0; u < 4; ++u) {
        const int r = r0 + u;
        const size_t idx = (size_t)r * NP + c;
        float v = acc[u] + M[idx] + 0.5f * M2[idx];
        if (r == c && r < NN) v += 1.0f;
        P[idx] = v;
        ((float*)&t)[u] = v;
    }
    *(float4*)(PT0 + (size_t)c * NP + r0) = t;   // r0 % 4 == 0, aligned
}

// ---------------------------------------------------------------------------
// forcing vectors via coalesced column-matvec passes (MT); seeds W level-0,
// writes out[0:302] = iv.
__global__ __launch_bounds__(320) void vec_kernel(
    const float* __restrict__ MT, const float* __restrict__ b0c,
    float* __restrict__ uv, const float* __restrict__ iv,
    float* __restrict__ W, float* __restrict__ out)
{
    __shared__ float ysB[NP], ysC[NP];
    const int tid = threadIdx.x;  // 320
    const float s = DTH / 8.0f;

    const float b0 = b0c[tid];
    const float cc = b0c[NP + tid];
    ysB[tid] = b0; ysC[tid] = cc;
    __syncthreads();

    float mb, mc, m2b, m2c, m3b, m3c;
    {
        float aB = 0.f, aC = 0.f;
        for (int k = 0; k < NP; ++k) {
            const float a = MT[(size_t)k * NP + tid];
            aB = fmaf(a, ysB[k], aB);
            aC = fmaf(a, ysC[k], aC);
        }
        mb = aB; mc = aC;
    }
    __syncthreads(); ysB[tid] = mb; ysC[tid] = mc; __syncthreads();
    {
        float aB = 0.f, aC = 0.f;
        for (int k = 0; k < NP; ++k) {
            const float a = MT[(size_t)k * NP + tid];
            aB = fmaf(a, ysB[k], aB);
            aC = fmaf(a, ysC[k], aC);
        }
        m2b = aB; m2c = aC;
    }
    __syncthreads(); ysB[tid] = m2b; ysC[tid] = m2c; __syncthreads();
    {
        float aB = 0.f, aC = 0.f;
        for (int k = 0; k < NP; ++k) {
            const float a = MT[(size_t)k * NP + tid];
            aB = fmaf(a, ysB[k], aB);
            aC = fmaf(a, ysC[k], aC);
        }
        m3b = aB; m3c = aC;
    }

    const float u1 = s * (b0 + mb + (1.0f / 3.0f) * (m2b + m3b));
    const float u2 = s * (3.0f * b0 + 2.0f * mb + m2b);
    const float u3 = s * (3.0f * b0 + mb);
    const float u4 = s * b0;
    const float dd = s * (8.0f * cc + 4.0f * mc + (4.0f / 3.0f) * m2c + (1.0f / 3.0f) * m3c);

    uv[tid]          = u1;
    uv[NP + tid]     = u2;
    uv[2 * NP + tid] = u3;
    uv[3 * NP + tid] = u4;
    uv[4 * NP + tid] = dd;

    W[(size_t)(0 << 8) * NP + tid] = dd;
    W[(size_t)(1 << 8) * NP + tid] = u1;
    W[(size_t)(2 << 8) * NP + tid] = u2;
    W[(size_t)(3 << 8) * NP + tid] = u3;
    W[(size_t)(4 << 8) * NP + tid] = u4;

    if (tid < NN) out[tid] = iv[tid];
}

// ---------------------------------------------------------------------------
// per-step Tout interp coefficients (np.interp clone)
__global__ void tau_kernel(const float* __restrict__ tout_t,
                           const float* __restrict__ tout_v,
                           const int* __restrict__ t0p,
                           float4* __restrict__ tau)
{
    const int n = blockIdx.x * 256 + threadIdx.x;
    if (n >= TS) return;
    const float tbase = 30.0f * (float)n + (float)(*t0p);
    float r[4];
    #pragma unroll
    for (int st = 0; st < 4; ++st) {
        const float x = tbase + 10.0f * (float)st;
        float res;
        if (x <= tout_t[0])            res = tout_v[0];
        else if (x >= tout_t[KN - 1])  res = tout_v[KN - 1];
        else {
            int k = (int)(x * (1.0f / 900.0f));
            if (k > KN - 2) k = KN - 2;
            if (k < 0) k = 0;
            if (x < tout_t[k] && k > 0) --k;
            else if (x >= tout_t[k + 1] && k < KN - 2) ++k;
            const float tk = tout_t[k], tk1 = tout_t[k + 1];
            const float wgt = (x - tk) / (tk1 - tk);
            res = tout_v[k] + wgt * (tout_v[k + 1] - tout_v[k]);
        }
        r[st] = res;
    }
    tau[n] = make_float4(r[0], r[1], r[2], r[3]);
}

// ---------------------------------------------------------------------------
// Fat ladder kernel, 320 threads. Blocks 0..319: squaring dst=src@src with
// fused transposed output into PT[j+1]. Blocks 320+: (j<8) W-doubling level j
// using PT[j]; (j>=8) pair-combine level j-8: Sout[k]=P^(2^j)@Sin[2k]+Sin[2k+1].
__global__ __launch_bounds__(320) void fat_kernel(
    const float* __restrict__ src, float* __restrict__ dst,
    float* __restrict__ PTall, int j, float* __restrict__ W,
    const float* __restrict__ Sin, float* __restrict__ Sout, int npairs)
{
    const int b = blockIdx.x;
    const int tid = threadIdx.x;
    if (b < 320) {
        // squaring: 5 rows x 64 cols per block
        const int w = tid >> 6, l = tid & 63;
        const int r = (b & 63) * 5 + w;
        const int c = (b >> 6) * 64 + l;
        const float* Ar = src + (size_t)r * NP;
        float acc = 0.f;
        #pragma unroll 4
        for (int k = 0; k < NP; ++k)
            acc = fmaf(Ar[k], src[(size_t)k * NP + c], acc);
        dst[(size_t)r * NP + c] = acc;
        PTall[(size_t)(j + 1) * NP * NP + (size_t)c * NP + r] = acc;
        return;
    }
    const float* PTj = PTall + (size_t)j * NP * NP;
    const int c0 = (b - 320) * 4;
    __shared__ float ys[4][NP];
    if (j < 8) {
        const int nc = 5 << j;
        #pragma unroll
        for (int u = 0; u < 4; ++u) {
            const int ci = c0 + u;
            float val = 0.0f;
            if (ci < nc) {
                const int v = ci >> j, mo = ci & ((1 << j) - 1);
                val = W[(size_t)((v << 8) + mo) * NP + tid];
            }
            ys[u][tid] = val;
        }
        __syncthreads();
        float a0 = 0.f, a1 = 0.f, a2 = 0.f, a3 = 0.f;
        #pragma unroll 4
        for (int k = 0; k < NP; ++k) {
            const float p = PTj[(size_t)k * NP + tid];
            a0 = fmaf(p, ys[0][k], a0);
            a1 = fmaf(p, ys[1][k], a1);
            a2 = fmaf(p, ys[2][k], a2);
            a3 = fmaf(p, ys[3][k], a3);
        }
        const float acc[4] = {a0, a1, a2, a3};
        #pragma unroll
        for (int u = 0; u < 4; ++u) {
            const int ci = c0 + u;
            if (ci < nc) {
                const int v = ci >> j, mo = ci & ((1 << j) - 1);
                W[(size_t)((v << 8) + (1 << j) + mo) * NP + tid] = acc[u];
            }
        }
    } else {
        #pragma unroll
        for (int u = 0; u < 4; ++u) {
            const int k = c0 + u;
            ys[u][tid] = (k < npairs) ? Sin[(size_t)(2 * k) * NP + tid] : 0.0f;
        }
        __syncthreads();
        float a0 = 0.f, a1 = 0.f, a2 = 0.f, a3 = 0.f;
        #pragma unroll 4
        for (int k = 0; k < NP; ++k) {
            const float p = PTj[(size_t)k * NP + tid];
            a0 = fmaf(p, ys[0][k], a0);
            a1 = fmaf(p, ys[1][k], a1);
            a2 = fmaf(p, ys[2][k], a2);
            a3 = fmaf(p, ys[3][k], a3);
        }
        const float acc[4] = {a0, a1, a2, a3};
        #pragma unroll
        for (int u = 0; u < 4; ++u) {
            const int k = c0 + u;
            if (k < npairs)
                Sout[(size_t)k * NP + tid] = acc[u] + Sin[(size_t)(2 * k + 1) * NP + tid];
        }
    }
}

// ---------------------------------------------------------------------------
// G_c = sum_m (Wd[m] + tau.x*W1[m] + ...), grid (5, 240) x 64; pad c>=234 -> 0.
__global__ void gsum_kernel(const float* __restrict__ W,
                            const float4* __restrict__ tau,
                            float* __restrict__ G)
{
    const int r = blockIdx.x * 64 + threadIdx.x;
    const int c = blockIdx.y;
    if (c >= N_BND) { G[(size_t)c * NP + r] = 0.0f; return; }
    const float* W0 = W;
    const float* W1 = W + 1 * (size_t)L_CHUNK * NP;
    const float* W2 = W + 2 * (size_t)L_CHUNK * NP;
    const float* W3 = W + 3 * (size_t)L_CHUNK * NP;
    const float* W4 = W + 4 * (size_t)L_CHUNK * NP;
    const int nbase = c * L_CHUNK + L_CHUNK - 1;
    float g = 0.f;
    for (int m = 0; m < L_CHUNK; ++m) {
        const float4 a = tau[nbase - m];
        const size_t o = (size_t)m * NP + r;
        float t = W0[o];
        t = fmaf(a.x, W1[o], t);
        t = fmaf(a.y, W2[o], t);
        t = fmaf(a.z, W3[o], t);
        t = fmaf(a.w, W4[o], t);
        g += t;
    }
    G[(size_t)c * NP + r] = g;
}

// ---------------------------------------------------------------------------
// 512-thread matvec engine, packed-fp32. Wave w owns cols [40w,40w+40) as 20
// vf2 pairs; lane l owns rows {l+64k}, k<5. Two accumulators per row (pk),
// summed at the end.
__device__ __forceinline__ void load_pfrag(const float* __restrict__ Psrc,
                                           vf2 p[5][20], int l, int w)
{
    #pragma unroll
    for (int k = 0; k < 5; ++k) {
        const float* Pr = Psrc + (size_t)(l + 64 * k) * NP + 40 * w;
        #pragma unroll
        for (int j4 = 0; j4 < 10; ++j4) {
            const float4 v4 = *(const float4*)(Pr + 4 * j4);
            vf2 a; a.x = v4.x; a.y = v4.y;
            vf2 b; b.x = v4.z; b.y = v4.w;
            p[k][2 * j4] = a;
            p[k][2 * j4 + 1] = b;
        }
    }
    // Break value provenance: compiler can no longer re-load P inside the
    // step loop (r5/r6 regression root cause).
    #pragma unroll
    for (int k = 0; k < 5; ++k)
        #pragma unroll
        for (int jj = 0; jj < 20; jj += 4)
            PIN4(p[k][jj], p[k][jj + 1], p[k][jj + 2], p[k][jj + 3]);
}

__device__ __forceinline__ float step_matvec(vf2 p[5][20],
                                             const float* __restrict__ ybuf,
                                             float* __restrict__ partial,
                                             int tid, int w, int l)
{
    vf2 a0 = {0.f, 0.f}, a1 = {0.f, 0.f}, a2 = {0.f, 0.f},
        a3 = {0.f, 0.f}, a4 = {0.f, 0.f};
    const float* yb = ybuf + 40 * w;
    #pragma unroll
    for (int j4 = 0; j4 < 10; ++j4) {
        const float4 yv = *(const float4*)(yb + 4 * j4);
        vf2 y01; y01.x = yv.x; y01.y = yv.y;
        vf2 y23; y23.x = yv.z; y23.y = yv.w;
        const int jj = 2 * j4;
        PKFMA(a0, p[0][jj], y01); PKFMA(a0, p[0][jj + 1], y23);
        PKFMA(a1, p[1][jj], y01); PKFMA(a1, p[1][jj + 1], y23);
        PKFMA(a2, p[2][jj], y01); PKFMA(a2, p[2][jj + 1], y23);
        PKFMA(a3, p[3][jj], y01); PKFMA(a3, p[3][jj + 1], y23);
        PKFMA(a4, p[4][jj], y01); PKFMA(a4, p[4][jj + 1], y23);
    }
    float* pw = partial + w * NP;
    pw[l]       = a0.x + a0.y;
    pw[l + 64]  = a1.x + a1.y;
    pw[l + 128] = a2.x + a2.y;
    pw[l + 192] = a3.x + a3.y;
    pw[l + 256] = a4.x + a4.y;
    __syncthreads();
    float s = 0.f;
    if (tid < NP) {
        #pragma unroll
        for (int k = 0; k < 8; ++k) s += partial[k * NP + tid];
    }
    return s;
}

// ---------------------------------------------------------------------------
// Level-2 boundary: Z_{g+1} = P^4096 Z_g + S4_g.  1 WG x 512, 15 steps.
__global__ ENGINE_BOUNDS void bscan_kernel(
    const float* __restrict__ PL16, const float* __restrict__ S4,
    const float* __restrict__ iv, float* __restrict__ Z)
{
    const int tid = threadIdx.x;
    const int w = tid >> 6, l = tid & 63;
    vf2 p[5][20];
    load_pfrag(PL16, p, l, w);

    __shared__ float ybuf[NP];
    __shared__ float partial[8 * NP];
    if (tid < NP) { const float y0 = (tid < NN) ? iv[tid] : 0.f; ybuf[tid] = y0; Z[tid] = y0; }
    __syncthreads();

    for (int g = 0; g < N_GRP; ++g) {
        const float s = step_matvec(p, ybuf, partial, tid, w, l);
        if (tid < NP) {
            const float yn = s + S4[(size_t)g * NP + tid];
            ybuf[tid] = yn;
            Z[(size_t)(g + 1) * NP + tid] = yn;
        }
        __syncthreads();
    }
}

// ---------------------------------------------------------------------------
// Level-2 refill: Y_{16g+i+1} = P^256 Y_{16g+i} + G_{16g+i}.  15 WGs x 512.
__global__ ENGINE_BOUNDS void brefill_kernel(
    const float* __restrict__ PL, const float* __restrict__ G,
    const float* __restrict__ Z, float* __restrict__ Y)
{
    const int tid = threadIdx.x;
    const int w = tid >> 6, l = tid & 63;
    vf2 p[5][20];
    load_pfrag(PL, p, l, w);

    __shared__ float ybuf[NP];
    __shared__ float partial[8 * NP];
    const int g = blockIdx.x;
    if (tid < NP) {
        const float z = Z[(size_t)g * NP + tid];
        ybuf[tid] = z;
        if (g == 0) Y[tid] = z;
    }
    __syncthreads();

    for (int i = 0; i < 16; ++i) {
        const int idx = 16 * g + i;
        if (idx >= N_BND) break;            // block-uniform
        const float s = step_matvec(p, ybuf, partial, tid, w, l);
        if (tid < NP) {
            const float yn = s + G[(size_t)idx * NP + tid];
            ybuf[tid] = yn;
            Y[(size_t)(idx + 1) * NP + tid] = yn;
        }
        __syncthreads();
    }
}

// ---------------------------------------------------------------------------
// Level-1 refill: grid 235 WGs x 512; WG c runs steps [256c, min(256c+256,TS)).
__global__ ENGINE_BOUNDS void refill_kernel(
    const float* __restrict__ P, const float* __restrict__ uv,
    const float4* __restrict__ tau, const float* __restrict__ Y,
    float* __restrict__ out)
{
    const int tid = threadIdx.x;
    const int w = tid >> 6, l = tid & 63;
    vf2 p[5][20];
    load_pfrag(P, p, l, w);

    float du0 = 0.f, du1 = 0.f, du2 = 0.f, du3 = 0.f, dd = 0.f;
    if (tid < NP) {
        du0 = uv[tid]; du1 = uv[NP + tid]; du2 = uv[2 * NP + tid];
        du3 = uv[3 * NP + tid]; dd = uv[4 * NP + tid];
    }

    __shared__ float ybuf[NP];
    __shared__ float partial[8 * NP];
    const int c = blockIdx.x;
    if (tid < NP) ybuf[tid] = Y[(size_t)c * NP + tid];
    __syncthreads();

    const int n0 = c * L_CHUNK;
    const int n1 = (n0 + L_CHUNK < TS) ? (n0 + L_CHUNK) : TS;
    for (int n = n0; n < n1; ++n) {
        const float s = step_matvec(p, ybuf, partial, tid, w, l);
        if (tid < NP) {
            const float4 a = tau[n];
            float yn = s + dd;
            yn = fmaf(a.x, du0, yn);
            yn = fmaf(a.y, du1, yn);
            yn = fmaf(a.z, du2, yn);
            yn = fmaf(a.w, du3, yn);
            ybuf[tid] = yn;
            if (tid < NN) out[(size_t)(n + 1) * NN + tid] = yn;
        }
        __syncthreads();
    }
}

// ---------------------------------------------------------------------------
extern "C" void kernel_launch(void* const* d_in, const int* in_sizes, int n_in,
                              void* d_out, int out_size, void* d_ws, size_t ws_size,
                              hipStream_t stream)
{
    const float* params = (const float*)d_in[0];
    const float* tlo    = (const float*)d_in[1];
    const float* thi    = (const float*)d_in[2];
    const float* B      = (const float*)d_in[3];
    const float* tout_t = (const float*)d_in[4];
    const float* tout_v = (const float*)d_in[5];
    const float* iv     = (const float*)d_in[6];
    const int*   t0     = (const int*)d_in[8];
    float* out = (float*)d_out;
    float* ws  = (float*)d_ws;

    float*  M    = ws + WS_M;
    float*  MT   = ws + WS_MT;
    float*  M2   = ws + WS_M2;
    float*  P    = ws + WS_P;
    float*  UV   = ws + WS_UV;
    float*  B0C  = ws + WS_B0C;
    float4* TAU  = (float4*)(ws + WS_TAU);
    float*  W    = ws + WS_W;
    float*  G    = ws + WS_G;
    float*  Y    = ws + WS_Y;
    float*  Z    = ws + WS_Z;
    float*  SA   = ws + WS_SA;
    float*  SB   = ws + WS_SB;
    float*  PL   = ws + WS_PL;
    float*  PA   = ws + WS_PA;
    float*  PB   = ws + WS_PB;
    float*  PT   = ws + WS_PT;     // slot j: transpose of P^(2^j)

    // Phase A: model build (fused)
    buildrow_kernel<<<NP, NP, 0, stream>>>(params, tlo, thi, M, MT);
    b0c_kernel<<<NP, 64, 0, stream>>>(params, tlo, thi, B, B0C);

    // Propagator: M2 = M@M; P = M2@(M/6+M2/24) + I + M + M2/2 (+ PT[0])
    matmul4r<<<dim3(5, 80), 64, 0, stream>>>(M, M, M2);
    matmulP<<<dim3(5, 80), 64, 0, stream>>>(M2, M, P, PT);

    // Forcing vectors (+W seed, +out row 0) and tau table
    vec_kernel<<<1, NP, 0, stream>>>(MT, B0C, UV, iv, W, out);
    tau_kernel<<<(TS + 255) / 256, 256, 0, stream>>>(tout_t, tout_v, t0, TAU);

    // Squaring ladder with riders. dst: j==7 -> PL (P^256), else PA/PB.
    // j<8 riders: W doubling; j>=8 riders: pair-combine of G sums.
    const float* Spp[5] = { G, SA, SB, SA, SB };   // ping-pong chain
    const float* src = P;
    for (int j = 0; j < 8; ++j) {
        float* dst = (j == 7) ? PL : ((j & 1) ? PB : PA);
        const int aux = ((5 << j) + 3) / 4;
        fat_kernel<<<320 + aux, 320, 0, stream>>>(src, dst, PT, j, W,
                                                  nullptr, nullptr, 0);
        src = dst;
    }
    // G needs complete W (after j=7 rider); pair-0 (inside j=8) needs G.
    gsum_kernel<<<dim3(5, NB_PAD), 64, 0, stream>>>(W, TAU, G);
    for (int j = 8; j < 12; ++j) {
        float* dst = (j & 1) ? PB : PA;
        const int npairs = 120 >> (j - 8);
        const int aux = (npairs + 3) / 4;
        fat_kernel<<<320 + aux, 320, 0, stream>>>(src, dst, PT, j, W,
                                                  Spp[j - 8], (float*)Spp[j - 7], npairs);
        src = dst;
    }
    // src == PB == P^4096; S4 == SB (15 group sums)

    // Level-2 boundary chain + level-2 refill of Y
    bscan_kernel<<<1, 512, 0, stream>>>(PB, SB, iv, Z);
    brefill_kernel<<<N_GRP, 512, 0, stream>>>(PL, G, Z, Y);

    // Level-1 parallel refill
    refill_kernel<<<N_CHUNK, 512, 0, stream>>>(P, UV, TAU, Y, out);
}

// Round 8
// 819.952 us; speedup vs baseline: 1.4317x; 1.0093x over previous
//
#include <hip/hip_runtime.h>
#include <math.h>

// Problem constants
#define NN     302      // state dim (N_ROOMS + 2)
#define MM     301      // input dim (N_ROOMS + 1)
#define NROOMS 300
#define NP     320      // padded dim
#define TS     59999    // number of steps
#define KN     2001     // tout knots
#define DTH    30.0f

// Time-chunking
#define L_CHUNK 256     // steps per chunk (level 1)
#define N_CHUNK 235     // ceil(59999/256) chunks
#define N_BND   234     // boundary steps
#define NB_PAD  240     // padded boundary count (15 groups of 16)
#define N_GRP   15      // level-2 groups

// Workspace layout (in floats)
#define WS_M    0        // 102400
#define WS_M2   102400   // 102400
#define WS_P    307200   // 102400
#define WS_UV   409600   // 1600
#define WS_B0C  411200   // 640
#define WS_TAU  412160   // 240000 (float4 x 59999)
#define WS_W    652160   // 5 x 256 x 320 = 409600
#define WS_G    1061760  // 240 x 320 = 76800
#define WS_Y    1138560  // 235 x 320 = 75200
#define WS_Z    1213760  // 16 x 320 = 5120
#define WS_SA   1218880  // 120 x 320 = 38400
#define WS_SB   1257280  // 60 x 320 = 19200
#define WS_PL   1276480  // 102400  P^256 row-major
#define WS_PA   1378880  // 102400  ladder ping
#define WS_PB   1481280  // 102400  ladder pong (ends as P^4096)
#define WS_PT   1583680  // 13 x 102400 (transposed powers, slot j = (P^(2^j))^T)
#define WS_MT   2914880  // 102400  M^T
                         // total 3017280 floats = 12.07 MB

typedef float vf2 __attribute__((ext_vector_type(2)));

// 512-thread engine: 8 waves; wave w owns cols [40w,40w+40) of P (rows l+64k,
// k<5). ONE barrier/step: wave w reduces rows 40w..40w+39 itself (the exact
// y-segment it reads next step) — no second barrier. No global memory ops in
// the step loop (r7 finding: per-step out-store forced vmcnt(0) drain at the
// barrier; 3 engines all stuck at ~1 us/step regardless of ALU load).
#define ENGINE_BOUNDS __launch_bounds__(512) __attribute__((amdgpu_waves_per_eu(2, 2)))
#define PKFMA(acc, a, b) asm("v_pk_fma_f32 %0, %1, %2, %0" : "+v"(acc) : "v"(a), "v"(b))
#define PIN4(a, b, c, d) asm volatile("" : "+v"(a), "+v"(b), "+v"(c), "+v"(d))

// ---------------------------------------------------------------------------
// Fused build: one block per row r. M = DTH*W with diag -= DTH*sum|W[r,:]|.
__global__ __launch_bounds__(320) void buildrow_kernel(
    const float* __restrict__ params, const float* __restrict__ tlo,
    const float* __restrict__ thi, float* __restrict__ M, float* __restrict__ MT)
{
    const int r = blockIdx.x;
    const int c = threadIdx.x;
    float wv = 0.0f;
    if (r < NN && c < NN) {
        const int idx = r * NN + c;
        const float x = 1.0f / (1.0f + expf(-params[idx]));
        wv = tlo[idx] + (thi[idx] - tlo[idx]) * x;
    }
    __shared__ float red[5];
    float s = fabsf(wv);
    #pragma unroll
    for (int off = 32; off > 0; off >>= 1) s += __shfl_xor(s, off, 64);
    if ((c & 63) == 0) red[c >> 6] = s;
    __syncthreads();
    const float rs = red[0] + red[1] + red[2] + red[3] + red[4];
    float v = DTH * wv;
    if (r == c) v -= DTH * rs;
    M[r * NP + c] = v;
    MT[(size_t)c * NP + r] = v;
}

// b0 = B[:,0], c = B[:,1:] @ Q  (wave per row; Q recomputed per block)
__global__ void b0c_kernel(const float* __restrict__ params,
                           const float* __restrict__ tlo,
                           const float* __restrict__ thi,
                           const float* __restrict__ B, float* __restrict__ b0c)
{
    __shared__ float Qs[NROOMS];
    const int r = blockIdx.x;
    const int l = threadIdx.x;
    for (int q = l; q < NROOMS; q += 64) {
        const int idx = NN * NN + q;
        const float x = 1.0f / (1.0f + expf(-params[idx]));
        Qs[q] = tlo[idx] + (thi[idx] - tlo[idx]) * x;
    }
    __syncthreads();
    if (r >= NN) {
        if (l == 0) { b0c[r] = 0.0f; b0c[NP + r] = 0.0f; }
        return;
    }
    float s = 0.0f;
    for (int q = l; q < NROOMS; q += 64) s = fmaf(B[r * MM + 1 + q], Qs[q], s);
    #pragma unroll
    for (int off = 32; off > 0; off >>= 1) s += __shfl_xor(s, off, 64);
    if (l == 0) { b0c[r] = B[r * MM]; b0c[NP + r] = s; }
}

// ---------------------------------------------------------------------------
// fp32 matmul 320^3, 4 rows per thread: grid (5, 80), block 64.  (M2 = M@M)
__global__ void matmul4r(const float* __restrict__ A, const float* __restrict__ B,
                         float* __restrict__ C)
{
    const int c = blockIdx.x * 64 + threadIdx.x;
    const int r0 = blockIdx.y * 4;
    const float* Ar = A + (size_t)r0 * NP;
    float a0 = 0.f, a1 = 0.f, a2 = 0.f, a3 = 0.f;
    #pragma unroll 4
    for (int k = 0; k < NP; ++k) {
        const float b = B[(size_t)k * NP + c];
        a0 = fmaf(Ar[k], b, a0);
        a1 = fmaf(Ar[NP + k], b, a1);
        a2 = fmaf(Ar[2 * NP + k], b, a2);
        a3 = fmaf(Ar[3 * NP + k], b, a3);
    }
    C[(size_t)r0 * NP + c] = a0;
    C[(size_t)(r0 + 1) * NP + c] = a1;
    C[(size_t)(r0 + 2) * NP + c] = a2;
    C[(size_t)(r0 + 3) * NP + c] = a3;
}

// P = M2 @ (M/6 + M2/24) + (I + M + M2/2); also PT0 = P^T.
__global__ void matmulP(const float* __restrict__ M2, const float* __restrict__ M,
                        float* __restrict__ P, float* __restrict__ PT0)
{
    const int c = blockIdx.x * 64 + threadIdx.x;
    const int r0 = blockIdx.y * 4;
    const float* Ar = M2 + (size_t)r0 * NP;
    float a0 = 0.f, a1 = 0.f, a2 = 0.f, a3 = 0.f;
    #pragma unroll 4
    for (int k = 0; k < NP; ++k) {
        const size_t o = (size_t)k * NP + c;
        const float b = (1.0f / 6.0f) * M[o] + (1.0f / 24.0f) * M2[o];
        a0 = fmaf(Ar[k], b, a0);
        a1 = fmaf(Ar[NP + k], b, a1);
        a2 = fmaf(Ar[2 * NP + k], b, a2);
        a3 = fmaf(Ar[3 * NP + k], b, a3);
    }
    float acc[4] = {a0, a1, a2, a3};
    float4 t;
    #pragma unroll
    for (int u = 0; u < 4; ++u) {
        const int r = r0 + u;
        const size_t idx = (size_t)r * NP + c;
        float v = acc[u] + M[idx] + 0.5f * M2[idx];
        if (r == c && r < NN) v += 1.0f;
        P[idx] = v;
        ((float*)&t)[u] = v;
    }
    *(float4*)(PT0 + (size_t)c * NP + r0) = t;
}

// ---------------------------------------------------------------------------
// forcing vectors via coalesced column-matvec passes (MT); seeds W level-0,
// writes out[0:302] = iv.
__global__ __launch_bounds__(320) void vec_kernel(
    const float* __restrict__ MT, const float* __restrict__ b0c,
    float* __restrict__ uv, const float* __restrict__ iv,
    float* __restrict__ W, float* __restrict__ out)
{
    __shared__ float ysB[NP], ysC[NP];
    const int tid = threadIdx.x;  // 320
    const float s = DTH / 8.0f;

    const float b0 = b0c[tid];
    const float cc = b0c[NP + tid];
    ysB[tid] = b0; ysC[tid] = cc;
    __syncthreads();

    float mb, mc, m2b, m2c, m3b, m3c;
    {
        float aB = 0.f, aC = 0.f;
        for (int k = 0; k < NP; ++k) {
            const float a = MT[(size_t)k * NP + tid];
            aB = fmaf(a, ysB[k], aB);
            aC = fmaf(a, ysC[k], aC);
        }
        mb = aB; mc = aC;
    }
    __syncthreads(); ysB[tid] = mb; ysC[tid] = mc; __syncthreads();
    {
        float aB = 0.f, aC = 0.f;
        for (int k = 0; k < NP; ++k) {
            const float a = MT[(size_t)k * NP + tid];
            aB = fmaf(a, ysB[k], aB);
            aC = fmaf(a, ysC[k], aC);
        }
        m2b = aB; m2c = aC;
    }
    __syncthreads(); ysB[tid] = m2b; ysC[tid] = m2c; __syncthreads();
    {
        float aB = 0.f, aC = 0.f;
        for (int k = 0; k < NP; ++k) {
            const float a = MT[(size_t)k * NP + tid];
            aB = fmaf(a, ysB[k], aB);
            aC = fmaf(a, ysC[k], aC);
        }
        m3b = aB; m3c = aC;
    }

    const float u1 = s * (b0 + mb + (1.0f / 3.0f) * (m2b + m3b));
    const float u2 = s * (3.0f * b0 + 2.0f * mb + m2b);
    const float u3 = s * (3.0f * b0 + mb);
    const float u4 = s * b0;
    const float dd = s * (8.0f * cc + 4.0f * mc + (4.0f / 3.0f) * m2c + (1.0f / 3.0f) * m3c);

    uv[tid]          = u1;
    uv[NP + tid]     = u2;
    uv[2 * NP + tid] = u3;
    uv[3 * NP + tid] = u4;
    uv[4 * NP + tid] = dd;

    W[(size_t)(0 << 8) * NP + tid] = dd;
    W[(size_t)(1 << 8) * NP + tid] = u1;
    W[(size_t)(2 << 8) * NP + tid] = u2;
    W[(size_t)(3 << 8) * NP + tid] = u3;
    W[(size_t)(4 << 8) * NP + tid] = u4;

    if (tid < NN) out[tid] = iv[tid];
}

// ---------------------------------------------------------------------------
// per-step Tout interp coefficients (np.interp clone)
__global__ void tau_kernel(const float* __restrict__ tout_t,
                           const float* __restrict__ tout_v,
                           const int* __restrict__ t0p,
                           float4* __restrict__ tau)
{
    const int n = blockIdx.x * 256 + threadIdx.x;
    if (n >= TS) return;
    const float tbase = 30.0f * (float)n + (float)(*t0p);
    float r[4];
    #pragma unroll
    for (int st = 0; st < 4; ++st) {
        const float x = tbase + 10.0f * (float)st;
        float res;
        if (x <= tout_t[0])            res = tout_v[0];
        else if (x >= tout_t[KN - 1])  res = tout_v[KN - 1];
        else {
            int k = (int)(x * (1.0f / 900.0f));
            if (k > KN - 2) k = KN - 2;
            if (k < 0) k = 0;
            if (x < tout_t[k] && k > 0) --k;
            else if (x >= tout_t[k + 1] && k < KN - 2) ++k;
            const float tk = tout_t[k], tk1 = tout_t[k + 1];
            const float wgt = (x - tk) / (tk1 - tk);
            res = tout_v[k] + wgt * (tout_v[k + 1] - tout_v[k]);
        }
        r[st] = res;
    }
    tau[n] = make_float4(r[0], r[1], r[2], r[3]);
}

// ---------------------------------------------------------------------------
// Fat ladder kernel (unchanged from r7).
__global__ __launch_bounds__(320) void fat_kernel(
    const float* __restrict__ src, float* __restrict__ dst,
    float* __restrict__ PTall, int j, float* __restrict__ W,
    const float* __restrict__ Sin, float* __restrict__ Sout, int npairs)
{
    const int b = blockIdx.x;
    const int tid = threadIdx.x;
    if (b < 320) {
        const int w = tid >> 6, l = tid & 63;
        const int r = (b & 63) * 5 + w;
        const int c = (b >> 6) * 64 + l;
        const float* Ar = src + (size_t)r * NP;
        float acc = 0.f;
        #pragma unroll 4
        for (int k = 0; k < NP; ++k)
            acc = fmaf(Ar[k], src[(size_t)k * NP + c], acc);
        dst[(size_t)r * NP + c] = acc;
        PTall[(size_t)(j + 1) * NP * NP + (size_t)c * NP + r] = acc;
        return;
    }
    const float* PTj = PTall + (size_t)j * NP * NP;
    const int c0 = (b - 320) * 4;
    __shared__ float ys[4][NP];
    if (j < 8) {
        const int nc = 5 << j;
        #pragma unroll
        for (int u = 0; u < 4; ++u) {
            const int ci = c0 + u;
            float val = 0.0f;
            if (ci < nc) {
                const int v = ci >> j, mo = ci & ((1 << j) - 1);
                val = W[(size_t)((v << 8) + mo) * NP + tid];
            }
            ys[u][tid] = val;
        }
        __syncthreads();
        float a0 = 0.f, a1 = 0.f, a2 = 0.f, a3 = 0.f;
        #pragma unroll 4
        for (int k = 0; k < NP; ++k) {
            const float p = PTj[(size_t)k * NP + tid];
            a0 = fmaf(p, ys[0][k], a0);
            a1 = fmaf(p, ys[1][k], a1);
            a2 = fmaf(p, ys[2][k], a2);
            a3 = fmaf(p, ys[3][k], a3);
        }
        const float acc[4] = {a0, a1, a2, a3};
        #pragma unroll
        for (int u = 0; u < 4; ++u) {
            const int ci = c0 + u;
            if (ci < nc) {
                const int v = ci >> j, mo = ci & ((1 << j) - 1);
                W[(size_t)((v << 8) + (1 << j) + mo) * NP + tid] = acc[u];
            }
        }
    } else {
        #pragma unroll
        for (int u = 0; u < 4; ++u) {
            const int k = c0 + u;
            ys[u][tid] = (k < npairs) ? Sin[(size_t)(2 * k) * NP + tid] : 0.0f;
        }
        __syncthreads();
        float a0 = 0.f, a1 = 0.f, a2 = 0.f, a3 = 0.f;
        #pragma unroll 4
        for (int k = 0; k < NP; ++k) {
            const float p = PTj[(size_t)k * NP + tid];
            a0 = fmaf(p, ys[0][k], a0);
            a1 = fmaf(p, ys[1][k], a1);
            a2 = fmaf(p, ys[2][k], a2);
            a3 = fmaf(p, ys[3][k], a3);
        }
        const float acc[4] = {a0, a1, a2, a3};
        #pragma unroll
        for (int u = 0; u < 4; ++u) {
            const int k = c0 + u;
            if (k < npairs)
                Sout[(size_t)k * NP + tid] = acc[u] + Sin[(size_t)(2 * k + 1) * NP + tid];
        }
    }
}

// ---------------------------------------------------------------------------
// G_c = sum_m (Wd[m] + tau.x*W1[m] + ...), grid (5, 240) x 64; pad c>=234 -> 0.
__global__ void gsum_kernel(const float* __restrict__ W,
                            const float4* __restrict__ tau,
                            float* __restrict__ G)
{
    const int r = blockIdx.x * 64 + threadIdx.x;
    const int c = blockIdx.y;
    if (c >= N_BND) { G[(size_t)c * NP + r] = 0.0f; return; }
    const float* W0 = W;
    const float* W1 = W + 1 * (size_t)L_CHUNK * NP;
    const float* W2 = W + 2 * (size_t)L_CHUNK * NP;
    const float* W3 = W + 3 * (size_t)L_CHUNK * NP;
    const float* W4 = W + 4 * (size_t)L_CHUNK * NP;
    const int nbase = c * L_CHUNK + L_CHUNK - 1;
    float g = 0.f;
    for (int m = 0; m < L_CHUNK; ++m) {
        const float4 a = tau[nbase - m];
        const size_t o = (size_t)m * NP + r;
        float t = W0[o];
        t = fmaf(a.x, W1[o], t);
        t = fmaf(a.y, W2[o], t);
        t = fmaf(a.z, W3[o], t);
        t = fmaf(a.w, W4[o], t);
        g += t;
    }
    G[(size_t)c * NP + r] = g;
}

// ---------------------------------------------------------------------------
// Engine helpers.
__device__ __forceinline__ void load_pfrag(const float* __restrict__ Psrc,
                                           vf2 p[5][20], int l, int w)
{
    #pragma unroll
    for (int k = 0; k < 5; ++k) {
        const float* Pr = Psrc + (size_t)(l + 64 * k) * NP + 40 * w;
        #pragma unroll
        for (int j4 = 0; j4 < 10; ++j4) {
            const float4 v4 = *(const float4*)(Pr + 4 * j4);
            vf2 a; a.x = v4.x; a.y = v4.y;
            vf2 b; b.x = v4.z; b.y = v4.w;
            p[k][2 * j4] = a;
            p[k][2 * j4 + 1] = b;
        }
    }
    #pragma unroll
    for (int k = 0; k < 5; ++k)
        #pragma unroll
        for (int jj = 0; jj < 20; jj += 4)
            PIN4(p[k][jj], p[k][jj + 1], p[k][jj + 2], p[k][jj + 3]);
}

// FMA phase: partial dots of rows {l+64k} over cols [40w,40w+40), written to pw.
__device__ __forceinline__ void fma_phase(vf2 p[5][20], const float* __restrict__ yb,
                                          float* __restrict__ pw, int l)
{
    vf2 a0 = {0.f, 0.f}, a1 = {0.f, 0.f}, a2 = {0.f, 0.f},
        a3 = {0.f, 0.f}, a4 = {0.f, 0.f};
    #pragma unroll
    for (int j4 = 0; j4 < 10; ++j4) {
        const float4 yv = *(const float4*)(yb + 4 * j4);
        vf2 y01; y01.x = yv.x; y01.y = yv.y;
        vf2 y23; y23.x = yv.z; y23.y = yv.w;
        const int jj = 2 * j4;
        PKFMA(a0, p[0][jj], y01); PKFMA(a0, p[0][jj + 1], y23);
        PKFMA(a1, p[1][jj], y01); PKFMA(a1, p[1][jj + 1], y23);
        PKFMA(a2, p[2][jj], y01); PKFMA(a2, p[2][jj + 1], y23);
        PKFMA(a3, p[3][jj], y01); PKFMA(a3, p[3][jj + 1], y23);
        PKFMA(a4, p[4][jj], y01); PKFMA(a4, p[4][jj + 1], y23);
    }
    pw[l]       = a0.x + a0.y;
    pw[l + 64]  = a1.x + a1.y;
    pw[l + 128] = a2.x + a2.y;
    pw[l + 192] = a3.x + a3.y;
    pw[l + 256] = a4.x + a4.y;
}

// Reduce rows r = 40w + l (l<40): sum the 8 waves' partials.
__device__ __forceinline__ float reduce8(const float* __restrict__ pb, int r)
{
    float s = pb[r];
    #pragma unroll
    for (int k = 1; k < 8; ++k) s += pb[k * NP + r];
    return s;
}

// ---------------------------------------------------------------------------
// Level-2 boundary: Z_{g+1} = P^4096 Z_g + S4_g.  1 WG x 512, 15 steps.
__global__ ENGINE_BOUNDS void bscan_kernel(
    const float* __restrict__ PL16, const float* __restrict__ S4,
    const float* __restrict__ iv, float* __restrict__ Z)
{
    const int tid = threadIdx.x;
    const int w = tid >> 6, l = tid & 63;
    vf2 p[5][20];
    load_pfrag(PL16, p, l, w);

    __shared__ float ybuf[NP];
    __shared__ float part[2 * 8 * NP];
    __shared__ float ring[N_GRP * NP];

    const int r = 40 * w + l;   // valid when l < 40
    float Sv[N_GRP];
    if (l < 40) {
        #pragma unroll
        for (int i = 0; i < N_GRP; ++i) Sv[i] = S4[(size_t)i * NP + r];
    }
    if (tid < NP) {
        const float y0 = (tid < NN) ? iv[tid] : 0.f;
        ybuf[tid] = y0;
        Z[tid] = y0;
    }
    __syncthreads();

    for (int g = 0; g < N_GRP; ++g) {
        float* pb = part + (g & 1) * 8 * NP;
        fma_phase(p, ybuf + 40 * w, pb + w * NP, l);
        __syncthreads();
        if (l < 40) {
            const float yn = reduce8(pb, r) + Sv[g];
            ybuf[r] = yn;
            ring[g * NP + r] = yn;
        }
    }
    __syncthreads();
    for (int s2 = 0; s2 < N_GRP; ++s2)
        for (int j = tid; j < NP; j += 512)
            Z[(size_t)(s2 + 1) * NP + j] = ring[s2 * NP + j];
}

// ---------------------------------------------------------------------------
// Level-2 refill: Y_{16g+i+1} = P^256 Y_{16g+i} + G_{16g+i}.  15 WGs x 512.
__global__ ENGINE_BOUNDS void brefill_kernel(
    const float* __restrict__ PL, const float* __restrict__ G,
    const float* __restrict__ Z, float* __restrict__ Y)
{
    const int tid = threadIdx.x;
    const int w = tid >> 6, l = tid & 63;
    vf2 p[5][20];
    load_pfrag(PL, p, l, w);

    __shared__ float ybuf[NP];
    __shared__ float part[2 * 8 * NP];
    __shared__ float ring[16 * NP];

    const int g = blockIdx.x;
    const int nsteps = (16 * g + 16 <= N_BND) ? 16 : (N_BND - 16 * g);
    const int r = 40 * w + l;
    float Gv[16];
    if (l < 40) {
        for (int i = 0; i < nsteps; ++i) Gv[i] = G[(size_t)(16 * g + i) * NP + r];
    }
    if (tid < NP) {
        const float z = Z[(size_t)g * NP + tid];
        ybuf[tid] = z;
        if (g == 0) Y[tid] = z;
    }
    __syncthreads();

    for (int i = 0; i < nsteps; ++i) {
        float* pb = part + (i & 1) * 8 * NP;
        fma_phase(p, ybuf + 40 * w, pb + w * NP, l);
        __syncthreads();
        if (l < 40) {
            const float yn = reduce8(pb, r) + Gv[i];
            ybuf[r] = yn;
            ring[i * NP + r] = yn;
        }
    }
    __syncthreads();
    for (int s2 = 0; s2 < nsteps; ++s2)
        for (int j = tid; j < NP; j += 512)
            Y[(size_t)(16 * g + 1 + s2) * NP + j] = ring[s2 * NP + j];
}

// ---------------------------------------------------------------------------
// Level-1 refill: grid 235 WGs x 512; WG c runs steps [256c, min(256c+256,TS)).
// One barrier/step; out rows buffered in a 16-slot LDS ring, flushed with
// coalesced stores every 16 steps; tau prefetched per window into LDS.
__global__ ENGINE_BOUNDS void refill_kernel(
    const float* __restrict__ P, const float* __restrict__ uv,
    const float4* __restrict__ tau, const float* __restrict__ Y,
    float* __restrict__ out)
{
    const int tid = threadIdx.x;
    const int w = tid >> 6, l = tid & 63;
    vf2 p[5][20];
    load_pfrag(P, p, l, w);

    __shared__ float ybuf[NP];
    __shared__ float part[2 * 8 * NP];
    __shared__ float ring[16 * NP];
    __shared__ float4 taus[16];

    const int r = 40 * w + l;
    float du0 = 0.f, du1 = 0.f, du2 = 0.f, du3 = 0.f, dd = 0.f;
    if (l < 40) {
        du0 = uv[r]; du1 = uv[NP + r]; du2 = uv[2 * NP + r];
        du3 = uv[3 * NP + r]; dd = uv[4 * NP + r];
    }

    const int c = blockIdx.x;
    const int n0 = c * L_CHUNK;
    const int n1 = (n0 + L_CHUNK < TS) ? (n0 + L_CHUNK) : TS;
    if (tid < NP) ybuf[tid] = Y[(size_t)c * NP + tid];
    int wstart = n0;
    if (tid < 16 && n0 + tid < n1) taus[tid] = tau[n0 + tid];
    __syncthreads();

    for (int n = n0; n < n1; ++n) {
        const int slot = n - wstart;
        float* pb = part + (n & 1) * 8 * NP;
        fma_phase(p, ybuf + 40 * w, pb + w * NP, l);
        __syncthreads();
        if (l < 40) {
            const float4 a = taus[slot];
            float yn = reduce8(pb, r) + dd;
            yn = fmaf(a.x, du0, yn);
            yn = fmaf(a.y, du1, yn);
            yn = fmaf(a.z, du2, yn);
            yn = fmaf(a.w, du3, yn);
            ybuf[r] = yn;
            ring[slot * NP + r] = yn;
        }
        if (slot == 15 || n == n1 - 1) {
            __syncthreads();   // ring + taus-read ordering
            const int nrows = slot + 1;
            for (int s2 = 0; s2 < nrows; ++s2) {
                const size_t row = (size_t)(wstart + 1 + s2);
                for (int j = tid; j < NN; j += 512)
                    out[row * NN + j] = ring[s2 * NP + j];
            }
            wstart = n + 1;
            if (tid < 16 && wstart + tid < n1) taus[tid] = tau[wstart + tid];
        }
    }
}

// ---------------------------------------------------------------------------
extern "C" void kernel_launch(void* const* d_in, const int* in_sizes, int n_in,
                              void* d_out, int out_size, void* d_ws, size_t ws_size,
                              hipStream_t stream)
{
    const float* params = (const float*)d_in[0];
    const float* tlo    = (const float*)d_in[1];
    const float* thi    = (const float*)d_in[2];
    const float* B      = (const float*)d_in[3];
    const float* tout_t = (const float*)d_in[4];
    const float* tout_v = (const float*)d_in[5];
    const float* iv     = (const float*)d_in[6];
    const int*   t0     = (const int*)d_in[8];
    float* out = (float*)d_out;
    float* ws  = (float*)d_ws;

    float*  M    = ws + WS_M;
    float*  MT   = ws + WS_MT;
    float*  M2   = ws + WS_M2;
    float*  P    = ws + WS_P;
    float*  UV   = ws + WS_UV;
    float*  B0C  = ws + WS_B0C;
    float4* TAU  = (float4*)(ws + WS_TAU);
    float*  W    = ws + WS_W;
    float*  G    = ws + WS_G;
    float*  Y    = ws + WS_Y;
    float*  Z    = ws + WS_Z;
    float*  SA   = ws + WS_SA;
    float*  SB   = ws + WS_SB;
    float*  PL   = ws + WS_PL;
    float*  PA   = ws + WS_PA;
    float*  PB   = ws + WS_PB;
    float*  PT   = ws + WS_PT;     // slot j: transpose of P^(2^j)

    // Phase A: model build (fused)
    buildrow_kernel<<<NP, NP, 0, stream>>>(params, tlo, thi, M, MT);
    b0c_kernel<<<NP, 64, 0, stream>>>(params, tlo, thi, B, B0C);

    // Propagator: M2 = M@M; P = M2@(M/6+M2/24) + I + M + M2/2 (+ PT[0])
    matmul4r<<<dim3(5, 80), 64, 0, stream>>>(M, M, M2);
    matmulP<<<dim3(5, 80), 64, 0, stream>>>(M2, M, P, PT);

    // Forcing vectors (+W seed, +out row 0) and tau table
    vec_kernel<<<1, NP, 0, stream>>>(MT, B0C, UV, iv, W, out);
    tau_kernel<<<(TS + 255) / 256, 256, 0, stream>>>(tout_t, tout_v, t0, TAU);

    // Squaring ladder with riders (j<8: W doubling; j>=8: pair-combine).
    const float* Spp[5] = { G, SA, SB, SA, SB };
    const float* src = P;
    for (int j = 0; j < 8; ++j) {
        float* dst = (j == 7) ? PL : ((j & 1) ? PB : PA);
        const int aux = ((5 << j) + 3) / 4;
        fat_kernel<<<320 + aux, 320, 0, stream>>>(src, dst, PT, j, W,
                                                  nullptr, nullptr, 0);
        src = dst;
    }
    gsum_kernel<<<dim3(5, NB_PAD), 64, 0, stream>>>(W, TAU, G);
    for (int j = 8; j < 12; ++j) {
        float* dst = (j & 1) ? PB : PA;
        const int npairs = 120 >> (j - 8);
        const int aux = (npairs + 3) / 4;
        fat_kernel<<<320 + aux, 320, 0, stream>>>(src, dst, PT, j, W,
                                                  Spp[j - 8], (float*)Spp[j - 7], npairs);
        src = dst;
    }
    // src == PB == P^4096; SB holds 15 group sums

    // Level-2 boundary chain + level-2 refill of Y
    bscan_kernel<<<1, 512, 0, stream>>>(PB, SB, iv, Z);
    brefill_kernel<<<N_GRP, 512, 0, stream>>>(PL, G, Z, Y);

    // Level-1 parallel refill
    refill_kernel<<<N_CHUNK, 512, 0, stream>>>(P, UV, TAU, Y, out);
}